// Round 2
// baseline (2094.304 us; speedup 1.0000x reference)
//
#include <hip/hip_runtime.h>
#include <math.h>

// ---------------------------------------------------------------------------
// Net_75505525064500 — round 2: atomic-scatter -> CSR-gather inversion.
// Round-1 evidence: 21.8M scattered f32 atomics cost ~32B HBM sector each
// (WRITE_SIZE 680 MB @ ~580 GB/s == dur). All segment sums/maxes are now
// gather-side over per-launch CSRs; only the histogram pass keeps atomics.
// Sizes: N=80000 (Cin=2), E=1280000, N1=40000 (C=8), N2=20000 (C=16), B=16.
// ---------------------------------------------------------------------------

__device__ __forceinline__ float eluf(float x) {
    return x > 0.f ? x : (expf(x) - 1.f);
}

struct Basis {
    float wx[2], wy[2], wz[2];
    int ibase;
};

// Open B-spline basis, degree 1, K=3/dim: v=p*2, i0=clip(floor(v),0,1), f=v-i0.
__device__ __forceinline__ Basis mkbasis(float px, float py, float pz) {
    float vx = px * 2.f, vy = py * 2.f, vz = pz * 2.f;
    float ix = fmaxf(fminf(floorf(vx), 1.f), 0.f);
    float iy = fmaxf(fminf(floorf(vy), 1.f), 0.f);
    float iz = fmaxf(fminf(floorf(vz), 1.f), 0.f);
    float fx = vx - ix, fy = vy - iy, fz = vz - iz;
    Basis b;
    b.wx[0] = 1.f - fx; b.wx[1] = fx;
    b.wy[0] = 1.f - fy; b.wy[1] = fy;
    b.wz[0] = 1.f - fz; b.wz[1] = fz;
    b.ibase = (int)ix + 3 * (int)iy + 9 * (int)iz;
    return b;
}

#define W1_STRIDE 20   // k*20 mod 32 spreads 27 k-rows over 8 bank-groups
#define W2_STRIDE 132  // measured 0 bank conflicts in round 1

// ---- phase 1: histograms + within-bin ranks (the only big atomic pass) ----
__global__ __launch_bounds__(256) void hist_kernel(
    const int* __restrict__ ei, const int* __restrict__ cluster1,
    const int* __restrict__ cluster2,
    int* __restrict__ deg, int* __restrict__ rank,
    int* __restrict__ cdeg, int* __restrict__ rankC,
    int* __restrict__ c2deg, int* __restrict__ rank2,
    int E, int N, int N1)
{
    int i = blockIdx.x * 256 + threadIdx.x;
    if (i < E)  rank[i]  = atomicAdd(&deg[ei[E + i]], 1);
    if (i < N)  rankC[i] = atomicAdd(&cdeg[cluster1[i]], 1);
    if (i < N1) rank2[i] = atomicAdd(&c2deg[cluster2[i]], 1);
}

// ---- phase 2: two-level exclusive scan, 3 arrays per launch ----
#define SCAN_CHUNK 4096  // 256 threads * 16 elems

__global__ __launch_bounds__(256) void scan_a(
    const int* __restrict__ in0, int* __restrict__ out0, int* __restrict__ aux0, int L0, int nb0,
    const int* __restrict__ in1, int* __restrict__ out1, int* __restrict__ aux1, int L1, int nb1,
    const int* __restrict__ in2, int* __restrict__ out2, int* __restrict__ aux2, int L2)
{
    int b = blockIdx.x;
    const int* in; int* out; int* aux; int L;
    if (b < nb0)            { in = in0; out = out0; aux = aux0; L = L0; }
    else if (b < nb0 + nb1) { b -= nb0; in = in1; out = out1; aux = aux1; L = L1; }
    else                    { b -= nb0 + nb1; in = in2; out = out2; aux = aux2; L = L2; }

    __shared__ int ls[256];
    int t = threadIdx.x;
    int base = b * SCAN_CHUNK + t * 16;
    int v[16];
    int s = 0;
#pragma unroll
    for (int j = 0; j < 16; ++j) {
        int val = (base + j < L) ? in[base + j] : 0;
        v[j] = s;       // exclusive within thread
        s += val;
    }
    ls[t] = s;
    __syncthreads();
    for (int off = 1; off < 256; off <<= 1) {
        int tv = (t >= off) ? ls[t - off] : 0;
        __syncthreads();
        ls[t] += tv;
        __syncthreads();
    }
    int excl = ls[t] - s;  // exclusive block-prefix for this thread
#pragma unroll
    for (int j = 0; j < 16; ++j)
        if (base + j < L) out[base + j] = excl + v[j];
    if (t == 255) aux[b] = ls[255];
}

__global__ __launch_bounds__(64) void scan_b(
    int* __restrict__ aux0, int nb0, int* __restrict__ off0, int L0,
    int* __restrict__ aux1, int nb1, int* __restrict__ off1, int L1,
    int* __restrict__ aux2, int nb2, int* __restrict__ off2, int L2)
{
    if (threadIdx.x != 0) return;
    int* aux; int nb; int* off; int L;
    if (blockIdx.x == 0)      { aux = aux0; nb = nb0; off = off0; L = L0; }
    else if (blockIdx.x == 1) { aux = aux1; nb = nb1; off = off1; L = L1; }
    else                      { aux = aux2; nb = nb2; off = off2; L = L2; }
    int run = 0;
    for (int j = 0; j < nb; ++j) { int tv = aux[j]; aux[j] = run; run += tv; }
    off[L] = run;  // grand total terminates the CSR
}

__global__ __launch_bounds__(256) void scan_c(
    int* __restrict__ out0, const int* __restrict__ aux0, int L0, int nb0,
    int* __restrict__ out1, const int* __restrict__ aux1, int L1, int nb1,
    int* __restrict__ out2, const int* __restrict__ aux2, int L2)
{
    int b = blockIdx.x;
    int* out; const int* aux; int L;
    if (b < nb0)            { out = out0; aux = aux0; L = L0; }
    else if (b < nb0 + nb1) { b -= nb0; out = out1; aux = aux1; L = L1; }
    else                    { b -= nb0 + nb1; out = out2; aux = aux2; L = L2; }
    int add = aux[b];
    int base = b * SCAN_CHUNK + threadIdx.x * 16;
#pragma unroll
    for (int j = 0; j < 16; ++j)
        if (base + j < L) out[base + j] += add;
}

// ---- phase 3: rank-based scatter (no atomics) ----
__global__ __launch_bounds__(256) void scat_kernel(
    const int* __restrict__ ei, const float* __restrict__ attr,
    const int* __restrict__ cluster1, const int* __restrict__ cluster2,
    const int* __restrict__ doffs, const int* __restrict__ rank,
    const int* __restrict__ coff, const int* __restrict__ rankC,
    const int* __restrict__ c2off, const int* __restrict__ rank2,
    int4* __restrict__ epack, int* __restrict__ esrc2,
    int* __restrict__ nidx, int* __restrict__ n1idx,
    int E, int N, int N1)
{
    int i = blockIdx.x * 256 + threadIdx.x;
    if (i < E) {
        int s = ei[i], d = ei[E + i];
        int p = doffs[d] + rank[i];
        epack[p] = make_int4(s, __float_as_int(attr[3 * i]),
                                __float_as_int(attr[3 * i + 1]),
                                __float_as_int(attr[3 * i + 2]));
        esrc2[p] = cluster1[s];
    }
    if (i < N)  nidx[coff[cluster1[i]] + rankC[i]] = i;
    if (i < N1) n1idx[c2off[cluster2[i]] + rank2[i]] = i;
}

// ---- level 1: thread-per-dst gather; writes mean message M1[d], no atomics ----
__global__ __launch_bounds__(256) void edge1_gather(
    const int4* __restrict__ epack, const int* __restrict__ doffs,
    const float2* __restrict__ x, const float* __restrict__ W1,
    float* __restrict__ M1, int N)
{
    __shared__ float lw[27 * W1_STRIDE];
    for (int i = threadIdx.x; i < 27 * 16; i += 256)
        lw[(i >> 4) * W1_STRIDE + (i & 15)] = W1[i];
    __syncthreads();

    int d = blockIdx.x * 256 + threadIdx.x;
    if (d >= N) return;
    int beg = doffs[d], end = doffs[d + 1];

    float acc[8];
#pragma unroll
    for (int o = 0; o < 8; ++o) acc[o] = 0.f;

    for (int e = beg; e < end; ++e) {
        int4 p = epack[e];
        Basis b = mkbasis(__int_as_float(p.y), __int_as_float(p.z), __int_as_float(p.w));
        float2 xv = x[p.x];
#pragma unroll
        for (int cz = 0; cz < 2; ++cz)
#pragma unroll
        for (int cy = 0; cy < 2; ++cy)
#pragma unroll
        for (int cx = 0; cx < 2; ++cx) {
            float w = b.wx[cx] * b.wy[cy] * b.wz[cz];
            int k = b.ibase + cx + 3 * cy + 9 * cz;
            const float* Wk = &lw[k * W1_STRIDE];
            float a = w * xv.x, bb = w * xv.y;
            const float4 wa0 = *(const float4*)&Wk[0];
            const float4 wa1 = *(const float4*)&Wk[4];
            const float4 wb0 = *(const float4*)&Wk[8];
            const float4 wb1 = *(const float4*)&Wk[12];
            acc[0] += a * wa0.x + bb * wb0.x;
            acc[1] += a * wa0.y + bb * wb0.y;
            acc[2] += a * wa0.z + bb * wb0.z;
            acc[3] += a * wa0.w + bb * wb0.w;
            acc[4] += a * wa1.x + bb * wb1.x;
            acc[5] += a * wa1.y + bb * wb1.y;
            acc[6] += a * wa1.z + bb * wb1.z;
            acc[7] += a * wa1.w + bb * wb1.w;
        }
    }
    float inv = 1.f / fmaxf((float)(end - beg), 1.f);
    float4* out = (float4*)&M1[(size_t)d * 8];
    out[0] = make_float4(acc[0] * inv, acc[1] * inv, acc[2] * inv, acc[3] * inv);
    out[1] = make_float4(acc[4] * inv, acc[5] * inv, acc[6] * inv, acc[7] * inv);
}

// ---- level 1 pool: thread-per-cluster gather-max, no atomics ----
__global__ __launch_bounds__(256) void node1_gather(
    const int* __restrict__ coff, const int* __restrict__ nidx,
    const float* __restrict__ M1, const float2* __restrict__ x,
    const float* __restrict__ root1, const float* __restrict__ b1,
    const int* __restrict__ batch,
    float* __restrict__ x1c, int* __restrict__ batch1, int N1)
{
    int c = blockIdx.x * 256 + threadIdx.x;
    if (c >= N1) return;
    int cb = coff[c], ce = coff[c + 1];
    float hm[8];
#pragma unroll
    for (int o = 0; o < 8; ++o) hm[o] = -INFINITY;
    int bm = 0;
    for (int idx = cb; idx < ce; ++idx) {
        int d = nidx[idx];
        float2 xv = x[d];
        const float4* m4 = (const float4*)&M1[(size_t)d * 8];
        float4 ma = m4[0], mb = m4[1];
        float mv[8] = {ma.x, ma.y, ma.z, ma.w, mb.x, mb.y, mb.z, mb.w};
#pragma unroll
        for (int o = 0; o < 8; ++o) {
            float h = eluf(mv[o] + xv.x * root1[o] + xv.y * root1[8 + o] + b1[o]);
            hm[o] = fmaxf(hm[o], h);
        }
        bm = max(bm, batch[d]);
    }
    if (ce == cb) {
#pragma unroll
        for (int o = 0; o < 8; ++o) hm[o] = 0.f;  // empty cluster -> 0 (ref isfinite mask)
    }
    float4* out = (float4*)&x1c[(size_t)c * 8];
    out[0] = make_float4(hm[0], hm[1], hm[2], hm[3]);
    out[1] = make_float4(hm[4], hm[5], hm[6], hm[7]);
    batch1[c] = bm;  // empty -> 0 matches maximum(segmax, 0)
}

// ---- level 2: thread-per-cluster gathers member dsts' edge bins, no atomics ----
__global__ __launch_bounds__(256) void edge2_gather(
    const int4* __restrict__ epack, const int* __restrict__ esrc2,
    const int* __restrict__ doffs, const int* __restrict__ coff,
    const int* __restrict__ nidx, const float4* __restrict__ x1c4,
    const float* __restrict__ W2, float* __restrict__ M2, int N1)
{
    __shared__ float lw[27 * W2_STRIDE];
    for (int i = threadIdx.x; i < 27 * 128; i += 256)
        lw[(i >> 7) * W2_STRIDE + (i & 127)] = W2[i];
    __syncthreads();

    int c = blockIdx.x * 256 + threadIdx.x;
    if (c >= N1) return;

    float acc[16];
#pragma unroll
    for (int o = 0; o < 16; ++o) acc[o] = 0.f;
    int cnt = 0;

    int cb = coff[c], ce = coff[c + 1];
    for (int idx = cb; idx < ce; ++idx) {
        int d = nidx[idx];
        int beg = doffs[d], end = doffs[d + 1];
        cnt += end - beg;
        for (int e = beg; e < end; ++e) {
            int4 p = epack[e];
            Basis b = mkbasis(__int_as_float(p.y), __int_as_float(p.z), __int_as_float(p.w));
            int s2 = esrc2[e];
            float4 xa = x1c4[2 * s2], xb = x1c4[2 * s2 + 1];
            float xr[8] = {xa.x, xa.y, xa.z, xa.w, xb.x, xb.y, xb.z, xb.w};
#pragma unroll
            for (int cz = 0; cz < 2; ++cz)
#pragma unroll
            for (int cy = 0; cy < 2; ++cy)
#pragma unroll
            for (int cx = 0; cx < 2; ++cx) {
                float w = b.wx[cx] * b.wy[cy] * b.wz[cz];
                int k = b.ibase + cx + 3 * cy + 9 * cz;
                const float* Wk = &lw[k * W2_STRIDE];
#pragma unroll
                for (int c8 = 0; c8 < 8; ++c8) {
                    float a = w * xr[c8];
                    const float4 w0 = *(const float4*)&Wk[c8 * 16 + 0];
                    const float4 w1 = *(const float4*)&Wk[c8 * 16 + 4];
                    const float4 w2 = *(const float4*)&Wk[c8 * 16 + 8];
                    const float4 w3 = *(const float4*)&Wk[c8 * 16 + 12];
                    acc[0]  += a * w0.x; acc[1]  += a * w0.y; acc[2]  += a * w0.z; acc[3]  += a * w0.w;
                    acc[4]  += a * w1.x; acc[5]  += a * w1.y; acc[6]  += a * w1.z; acc[7]  += a * w1.w;
                    acc[8]  += a * w2.x; acc[9]  += a * w2.y; acc[10] += a * w2.z; acc[11] += a * w2.w;
                    acc[12] += a * w3.x; acc[13] += a * w3.y; acc[14] += a * w3.z; acc[15] += a * w3.w;
                }
            }
        }
    }
    float inv = 1.f / fmaxf((float)cnt, 1.f);
    float4* out = (float4*)&M2[(size_t)c * 16];
#pragma unroll
    for (int q = 0; q < 4; ++q)
        out[q] = make_float4(acc[4 * q] * inv, acc[4 * q + 1] * inv,
                             acc[4 * q + 2] * inv, acc[4 * q + 3] * inv);
}

// ---- level 2 pool + graph mean, fused: tiny atomic tail (20000 rows) ----
__global__ __launch_bounds__(256) void node2_gather(
    const int* __restrict__ c2off, const int* __restrict__ n1idx,
    const float* __restrict__ M2, const float* __restrict__ x1c,
    const float* __restrict__ root2, const float* __restrict__ b2,
    const int* __restrict__ batch1,
    float* __restrict__ gsum, float* __restrict__ gcnt, int N2)
{
    int c2 = blockIdx.x * 256 + threadIdx.x;
    if (c2 >= N2) return;
    int cb = c2off[c2], ce = c2off[c2 + 1];
    float hm[16];
#pragma unroll
    for (int o = 0; o < 16; ++o) hm[o] = -INFINITY;
    int bm = 0;
    for (int idx = cb; idx < ce; ++idx) {
        int n1 = n1idx[idx];
        const float4* xr4 = (const float4*)&x1c[(size_t)n1 * 8];
        float4 xa = xr4[0], xb = xr4[1];
        float xr[8] = {xa.x, xa.y, xa.z, xa.w, xb.x, xb.y, xb.z, xb.w};
#pragma unroll
        for (int o = 0; o < 16; ++o) {
            float v = M2[(size_t)n1 * 16 + o] + b2[o];
#pragma unroll
            for (int c8 = 0; c8 < 8; ++c8) v += xr[c8] * root2[c8 * 16 + o];
            hm[o] = fmaxf(hm[o], eluf(v));
        }
        bm = max(bm, batch1[n1]);
    }
    if (ce == cb) {
#pragma unroll
        for (int o = 0; o < 16; ++o) hm[o] = 0.f;  // empty cluster2 -> zero row, graph 0
    }
    float* gs = &gsum[(size_t)bm * 16];
#pragma unroll
    for (int o = 0; o < 16; ++o) unsafeAtomicAdd(&gs[o], hm[o]);
    unsafeAtomicAdd(&gcnt[bm], 1.f);
}

// ---- head: g = gsum/max(gcnt,1); elu(g@fc1+b); elu(h@fc2+b) -> out[B] ----
__global__ __launch_bounds__(256) void head_kernel(
    const float* __restrict__ gsum, const float* __restrict__ gcnt,
    const float* __restrict__ fc1_w, const float* __restrict__ fc1_b,
    const float* __restrict__ fc2_w, const float* __restrict__ fc2_b,
    float* __restrict__ out, int B)
{
    __shared__ float g[16 * 16];
    __shared__ float h1[16 * 64];
    int t = threadIdx.x;
    if (t < B * 16) {
        int b = t >> 4;
        g[t] = gsum[t] / fmaxf(gcnt[b], 1.f);
    }
    __syncthreads();
    for (int j = t; j < B * 64; j += 256) {
        int b = j >> 6, jj = j & 63;
        float s = fc1_b[jj];
#pragma unroll
        for (int c = 0; c < 16; ++c) s += g[b * 16 + c] * fc1_w[c * 64 + jj];
        h1[j] = eluf(s);
    }
    __syncthreads();
    if (t < B) {
        float s = fc2_b[0];
#pragma unroll
        for (int j = 0; j < 64; ++j) s += h1[t * 64 + j] * fc2_w[j];
        out[t] = eluf(s);
    }
}

extern "C" void kernel_launch(void* const* d_in, const int* in_sizes, int n_in,
                              void* d_out, int out_size, void* d_ws, size_t ws_size,
                              hipStream_t stream)
{
    const float* x        = (const float*)d_in[0];
    const int*   ei       = (const int*)  d_in[1];
    const float* attr     = (const float*)d_in[2];
    const int*   batch    = (const int*)  d_in[3];
    const int*   cluster1 = (const int*)  d_in[4];
    const int*   cluster2 = (const int*)  d_in[5];
    const float* W1       = (const float*)d_in[6];
    const float* root1    = (const float*)d_in[7];
    const float* b1       = (const float*)d_in[8];
    const float* W2       = (const float*)d_in[9];
    const float* root2    = (const float*)d_in[10];
    const float* b2       = (const float*)d_in[11];
    const float* fc1_w    = (const float*)d_in[12];
    const float* fc1_b    = (const float*)d_in[13];
    const float* fc2_w    = (const float*)d_in[14];
    const float* fc2_b    = (const float*)d_in[15];

    const int N  = in_sizes[0] / 2;
    const int E  = in_sizes[1] / 2;
    const int N1 = in_sizes[5];
    const int N2 = N1 / 2;
    const int B  = out_size;

    const int nb0 = (N  + SCAN_CHUNK - 1) / SCAN_CHUNK;
    const int nb1 = (N1 + SCAN_CHUNK - 1) / SCAN_CHUNK;
    const int nb2 = (N2 + SCAN_CHUNK - 1) / SCAN_CHUNK;

    int* wi = (int*)d_ws;
    size_t off = 0;
    auto alloc = [&](size_t n, size_t align = 1) {
        off = (off + align - 1) & ~(align - 1);
        size_t r = off; off += n; return r;
    };
    // memset region (zero-init): deg, cdeg, c2deg, gsum, gcnt
    int*   deg    = wi + alloc(N);
    int*   cdeg   = wi + alloc(N1);
    int*   c2deg  = wi + alloc(N2);
    float* gsum   = (float*)(wi + alloc((size_t)B * 16));
    float* gcnt   = (float*)(wi + alloc(B));
    const size_t zcount = off;
    // rest (fully overwritten before read)
    int*   doffs  = wi + alloc(N + 1);
    int*   coff   = wi + alloc(N1 + 1);
    int*   c2off  = wi + alloc(N2 + 1);
    int*   auxA   = wi + alloc(nb0);
    int*   auxB   = wi + alloc(nb1);
    int*   auxC   = wi + alloc(nb2);
    int*   rank   = wi + alloc(E);
    int*   rankC  = wi + alloc(N);
    int*   rank2  = wi + alloc(N1);
    int4*  epack  = (int4*)(wi + alloc((size_t)E * 4, 4));
    int*   esrc2  = wi + alloc(E);
    int*   nidx   = wi + alloc(N);
    int*   n1idx  = wi + alloc(N1);
    float* M1     = (float*)(wi + alloc((size_t)N * 8));
    float* x1c    = (float*)(wi + alloc((size_t)N1 * 8));
    int*   batch1 = wi + alloc(N1);
    float* M2     = (float*)(wi + alloc((size_t)N1 * 16));

    hipMemsetAsync(d_ws, 0, zcount * sizeof(int), stream);

    const int eb = (E + 255) / 256;
    hist_kernel<<<eb, 256, 0, stream>>>(ei, cluster1, cluster2,
                                        deg, rank, cdeg, rankC, c2deg, rank2, E, N, N1);
    scan_a<<<nb0 + nb1 + nb2, 256, 0, stream>>>(deg, doffs, auxA, N, nb0,
                                                cdeg, coff, auxB, N1, nb1,
                                                c2deg, c2off, auxC, N2);
    scan_b<<<3, 64, 0, stream>>>(auxA, nb0, doffs, N,
                                 auxB, nb1, coff, N1,
                                 auxC, nb2, c2off, N2);
    scan_c<<<nb0 + nb1 + nb2, 256, 0, stream>>>(doffs, auxA, N, nb0,
                                                coff, auxB, N1, nb1,
                                                c2off, auxC, N2);
    scat_kernel<<<eb, 256, 0, stream>>>(ei, attr, cluster1, cluster2,
                                        doffs, rank, coff, rankC, c2off, rank2,
                                        epack, esrc2, nidx, n1idx, E, N, N1);
    edge1_gather<<<(N + 255) / 256, 256, 0, stream>>>(
        epack, doffs, (const float2*)x, W1, M1, N);
    node1_gather<<<(N1 + 255) / 256, 256, 0, stream>>>(
        coff, nidx, M1, (const float2*)x, root1, b1, batch, x1c, batch1, N1);
    edge2_gather<<<(N1 + 255) / 256, 256, 0, stream>>>(
        epack, esrc2, doffs, coff, nidx, (const float4*)x1c, W2, M2, N1);
    node2_gather<<<(N2 + 255) / 256, 256, 0, stream>>>(
        c2off, n1idx, M2, x1c, root2, b2, batch1, gsum, gcnt, N2);
    head_kernel<<<1, 256, 0, stream>>>(gsum, gcnt, fc1_w, fc1_b, fc2_w, fc2_b,
                                       (float*)d_out, B);
}

// Round 3
// 584.890 us; speedup vs baseline: 3.5807x; 3.5807x over previous
//
#include <hip/hip_runtime.h>
#include <math.h>

// ---------------------------------------------------------------------------
// Net_75505525064500 — round 3.
// R1 evidence: scattered f32 atomics = 32B HBM sectors @ ~580 GB/s (680 MB).
// R2 evidence: thread-per-cluster gather = 157 blocks, Occupancy 4%, serial
//   per-thread loops -> latency-bound (1000 us at 3-9% VALUBusy).
// R3: edge-parallel compute (coalesced) + one 4B/edge perm scatter + indexed
//   reduces with >=640K threads each; per-edge W2 blend replaced by a
//   precomputed xW2[s2][k][16] table (69 MB, LLC-resident gathers).
// Sizes: N=80000 (Cin=2), E=1280000, N1=40000 (C=8), N2=20000 (C=16), B=16.
// ---------------------------------------------------------------------------

__device__ __forceinline__ float eluf(float x) {
    return x > 0.f ? x : (expf(x) - 1.f);
}

#define W1_STRIDE 20
#define W2_STRIDE 132  // measured 0 LDS bank conflicts (R1/R2)

__device__ __constant__ int KOFF[8] = {0, 1, 3, 4, 9, 10, 12, 13};  // cx+3cy+9cz

// ---- phase 1: histograms + within-bin ranks (the only big atomic pass) ----
__global__ __launch_bounds__(256) void hist_kernel(
    const int* __restrict__ ei, const int* __restrict__ cluster1,
    const int* __restrict__ cluster2,
    int* __restrict__ deg, int* __restrict__ rank,
    int* __restrict__ cdeg, int* __restrict__ rankC,
    int* __restrict__ c2deg, int* __restrict__ rank2,
    int E, int N, int N1)
{
    int i = blockIdx.x * 256 + threadIdx.x;
    if (i < E)  rank[i]  = atomicAdd(&deg[ei[E + i]], 1);
    if (i < N)  rankC[i] = atomicAdd(&cdeg[cluster1[i]], 1);
    if (i < N1) rank2[i] = atomicAdd(&c2deg[cluster2[i]], 1);
}

// ---- phase 2: two-level exclusive scan, 3 arrays per launch ----
#define SCAN_CHUNK 4096

__global__ __launch_bounds__(256) void scan_a(
    const int* __restrict__ in0, int* __restrict__ out0, int* __restrict__ aux0, int L0, int nb0,
    const int* __restrict__ in1, int* __restrict__ out1, int* __restrict__ aux1, int L1, int nb1,
    const int* __restrict__ in2, int* __restrict__ out2, int* __restrict__ aux2, int L2)
{
    int b = blockIdx.x;
    const int* in; int* out; int* aux; int L;
    if (b < nb0)            { in = in0; out = out0; aux = aux0; L = L0; }
    else if (b < nb0 + nb1) { b -= nb0; in = in1; out = out1; aux = aux1; L = L1; }
    else                    { b -= nb0 + nb1; in = in2; out = out2; aux = aux2; L = L2; }

    __shared__ int ls[256];
    int t = threadIdx.x;
    int base = b * SCAN_CHUNK + t * 16;
    int v[16];
    int s = 0;
#pragma unroll
    for (int j = 0; j < 16; ++j) {
        int val = (base + j < L) ? in[base + j] : 0;
        v[j] = s;
        s += val;
    }
    ls[t] = s;
    __syncthreads();
    for (int off = 1; off < 256; off <<= 1) {
        int tv = (t >= off) ? ls[t - off] : 0;
        __syncthreads();
        ls[t] += tv;
        __syncthreads();
    }
    int excl = ls[t] - s;
#pragma unroll
    for (int j = 0; j < 16; ++j)
        if (base + j < L) out[base + j] = excl + v[j];
    if (t == 255) aux[b] = ls[255];
}

__global__ __launch_bounds__(64) void scan_b(
    int* __restrict__ aux0, int nb0, int* __restrict__ off0, int L0,
    int* __restrict__ aux1, int nb1, int* __restrict__ off1, int L1,
    int* __restrict__ aux2, int nb2, int* __restrict__ off2, int L2)
{
    if (threadIdx.x != 0) return;
    int* aux; int nb; int* off; int L;
    if (blockIdx.x == 0)      { aux = aux0; nb = nb0; off = off0; L = L0; }
    else if (blockIdx.x == 1) { aux = aux1; nb = nb1; off = off1; L = L1; }
    else                      { aux = aux2; nb = nb2; off = off2; L = L2; }
    int run = 0;
    for (int j = 0; j < nb; ++j) { int tv = aux[j]; aux[j] = run; run += tv; }
    off[L] = run;
}

__global__ __launch_bounds__(256) void scan_c(
    int* __restrict__ out0, const int* __restrict__ aux0, int L0, int nb0,
    int* __restrict__ out1, const int* __restrict__ aux1, int L1, int nb1,
    int* __restrict__ out2, const int* __restrict__ aux2, int L2)
{
    int b = blockIdx.x;
    int* out; const int* aux; int L;
    if (b < nb0)            { out = out0; aux = aux0; L = L0; }
    else if (b < nb0 + nb1) { b -= nb0; out = out1; aux = aux1; L = L1; }
    else                    { b -= nb0 + nb1; out = out2; aux = aux2; L = L2; }
    int add = aux[b];
    int base = b * SCAN_CHUNK + threadIdx.x * 16;
#pragma unroll
    for (int j = 0; j < 16; ++j)
        if (base + j < L) out[base + j] += add;
}

// ---- phase 3 (fused): perm scatter + edge-parallel msg1/basis, coalesced ----
__global__ __launch_bounds__(256) void scatA_kernel(
    const int* __restrict__ ei, const float* __restrict__ attr,
    const int* __restrict__ cluster1, const int* __restrict__ cluster2,
    const float2* __restrict__ x, const float* __restrict__ W1,
    const int* __restrict__ doffs, const int* __restrict__ rank,
    const int* __restrict__ coff, const int* __restrict__ rankC,
    const int* __restrict__ c2off, const int* __restrict__ rank2,
    int* __restrict__ perm, int* __restrict__ nidx, int* __restrict__ n1idx,
    float* __restrict__ msg1, int4* __restrict__ wmeta,
    int E, int N, int N1)
{
    __shared__ float lw[27 * W1_STRIDE];
    for (int i = threadIdx.x; i < 27 * 16; i += 256)
        lw[(i >> 4) * W1_STRIDE + (i & 15)] = W1[i];
    __syncthreads();

    int i = blockIdx.x * 256 + threadIdx.x;
    if (i < E) {
        int s = ei[i], d = ei[E + i];
        perm[doffs[d] + rank[i]] = i;  // the only E-sized scatter

        float vx = attr[3 * i] * 2.f, vy = attr[3 * i + 1] * 2.f, vz = attr[3 * i + 2] * 2.f;
        float ix = fmaxf(fminf(floorf(vx), 1.f), 0.f);
        float iy = fmaxf(fminf(floorf(vy), 1.f), 0.f);
        float iz = fmaxf(fminf(floorf(vz), 1.f), 0.f);
        float fx = vx - ix, fy = vy - iy, fz = vz - iz;
        int ibase = (int)ix + 3 * (int)iy + 9 * (int)iz;

        float2 xv = x[s];
        float wxv[2] = {1.f - fx, fx}, wyv[2] = {1.f - fy, fy}, wzv[2] = {1.f - fz, fz};
        float m[8];
#pragma unroll
        for (int o = 0; o < 8; ++o) m[o] = 0.f;
#pragma unroll
        for (int j = 0; j < 8; ++j) {
            int cx = j & 1, cy = (j >> 1) & 1, cz = j >> 2;
            float w = wxv[cx] * wyv[cy] * wzv[cz];
            const float* Wk = &lw[(ibase + cx + 3 * cy + 9 * cz) * W1_STRIDE];
            float a = w * xv.x, bb = w * xv.y;
            const float4 wa0 = *(const float4*)&Wk[0];
            const float4 wa1 = *(const float4*)&Wk[4];
            const float4 wb0 = *(const float4*)&Wk[8];
            const float4 wb1 = *(const float4*)&Wk[12];
            m[0] += a * wa0.x + bb * wb0.x;
            m[1] += a * wa0.y + bb * wb0.y;
            m[2] += a * wa0.z + bb * wb0.z;
            m[3] += a * wa0.w + bb * wb0.w;
            m[4] += a * wa1.x + bb * wb1.x;
            m[5] += a * wa1.y + bb * wb1.y;
            m[6] += a * wa1.z + bb * wb1.z;
            m[7] += a * wa1.w + bb * wb1.w;
        }
        float4* mo = (float4*)&msg1[(size_t)i * 8];
        mo[0] = make_float4(m[0], m[1], m[2], m[3]);
        mo[1] = make_float4(m[4], m[5], m[6], m[7]);
        wmeta[i] = make_int4(__float_as_int(fx), __float_as_int(fy), __float_as_int(fz),
                             (cluster1[s] << 5) | ibase);
    }
    if (i < N)  nidx[coff[cluster1[i]] + rankC[i]] = i;
    if (i < N1) n1idx[c2off[cluster2[i]] + rank2[i]] = i;
}

// ---- reduce msg1 by dst: thread per (dst, channel) ----
__global__ __launch_bounds__(256) void reduce1_kernel(
    const int* __restrict__ perm, const int* __restrict__ doffs,
    const float* __restrict__ msg1, float* __restrict__ M1, int N)
{
    int t = blockIdx.x * 256 + threadIdx.x;
    if (t >= N * 8) return;
    int d = t >> 3, ch = t & 7;
    int beg = doffs[d], end = doffs[d + 1];
    float acc = 0.f;
    for (int p = beg; p < end; ++p)
        acc += msg1[(size_t)perm[p] * 8 + ch];
    M1[t] = acc / fmaxf((float)(end - beg), 1.f);
}

// ---- level 1 pool: thread-per-cluster gather-max (tiny work) ----
__global__ __launch_bounds__(256) void node1_gather(
    const int* __restrict__ coff, const int* __restrict__ nidx,
    const float* __restrict__ M1, const float2* __restrict__ x,
    const float* __restrict__ root1, const float* __restrict__ b1,
    const int* __restrict__ batch,
    float* __restrict__ x1c, int* __restrict__ batch1, int N1)
{
    int c = blockIdx.x * 256 + threadIdx.x;
    if (c >= N1) return;
    int cb = coff[c], ce = coff[c + 1];
    float hm[8];
#pragma unroll
    for (int o = 0; o < 8; ++o) hm[o] = -INFINITY;
    int bm = 0;
    for (int idx = cb; idx < ce; ++idx) {
        int d = nidx[idx];
        float2 xv = x[d];
        const float4* m4 = (const float4*)&M1[(size_t)d * 8];
        float4 ma = m4[0], mb = m4[1];
        float mv[8] = {ma.x, ma.y, ma.z, ma.w, mb.x, mb.y, mb.z, mb.w};
#pragma unroll
        for (int o = 0; o < 8; ++o) {
            float h = eluf(mv[o] + xv.x * root1[o] + xv.y * root1[8 + o] + b1[o]);
            hm[o] = fmaxf(hm[o], h);
        }
        bm = max(bm, batch[d]);
    }
    if (ce == cb) {
#pragma unroll
        for (int o = 0; o < 8; ++o) hm[o] = 0.f;
    }
    float4* out = (float4*)&x1c[(size_t)c * 8];
    out[0] = make_float4(hm[0], hm[1], hm[2], hm[3]);
    out[1] = make_float4(hm[4], hm[5], hm[6], hm[7]);
    batch1[c] = bm;
}

// ---- xW2 table: thread per (s2,k) computes x1c[s2] @ W2[k] -> 16 floats ----
__global__ __launch_bounds__(256) void xw2_kernel(
    const float4* __restrict__ x1c4, const float* __restrict__ W2,
    float* __restrict__ xW2, int N1)
{
    __shared__ float lw[27 * W2_STRIDE];
    for (int i = threadIdx.x; i < 27 * 128; i += 256)
        lw[(i >> 7) * W2_STRIDE + (i & 127)] = W2[i];
    __syncthreads();

    int t = blockIdx.x * 256 + threadIdx.x;
    if (t >= N1 * 27) return;
    int s2 = t / 27;
    int k = t - 27 * s2;
    float4 xa = x1c4[2 * s2], xb = x1c4[2 * s2 + 1];
    float xr[8] = {xa.x, xa.y, xa.z, xa.w, xb.x, xb.y, xb.z, xb.w};
    float acc[16];
#pragma unroll
    for (int o = 0; o < 16; ++o) acc[o] = 0.f;
    const float* Wk = &lw[k * W2_STRIDE];
#pragma unroll
    for (int c = 0; c < 8; ++c) {
        float a = xr[c];
        const float4 w0 = *(const float4*)&Wk[c * 16 + 0];
        const float4 w1 = *(const float4*)&Wk[c * 16 + 4];
        const float4 w2 = *(const float4*)&Wk[c * 16 + 8];
        const float4 w3 = *(const float4*)&Wk[c * 16 + 12];
        acc[0]  += a * w0.x; acc[1]  += a * w0.y; acc[2]  += a * w0.z; acc[3]  += a * w0.w;
        acc[4]  += a * w1.x; acc[5]  += a * w1.y; acc[6]  += a * w1.z; acc[7]  += a * w1.w;
        acc[8]  += a * w2.x; acc[9]  += a * w2.y; acc[10] += a * w2.z; acc[11] += a * w2.w;
        acc[12] += a * w3.x; acc[13] += a * w3.y; acc[14] += a * w3.z; acc[15] += a * w3.w;
    }
    float4* out = (float4*)&xW2[(size_t)t * 16];
#pragma unroll
    for (int q = 0; q < 4; ++q)
        out[q] = make_float4(acc[4 * q], acc[4 * q + 1], acc[4 * q + 2], acc[4 * q + 3]);
}

// ---- level 2 reduce: thread per (cluster, out-channel); gathers xW2 rows ----
__global__ __launch_bounds__(256) void reduce2_kernel(
    const int* __restrict__ coff, const int* __restrict__ nidx,
    const int* __restrict__ doffs, const int* __restrict__ perm,
    const int4* __restrict__ wmeta, const float* __restrict__ xW2,
    float* __restrict__ M2, int N1)
{
    int t = blockIdx.x * 256 + threadIdx.x;
    if (t >= N1 * 16) return;
    int c = t >> 4, o = t & 15;
    float acc = 0.f;
    int cnt = 0;
    int cb = coff[c], ce = coff[c + 1];
    for (int idx = cb; idx < ce; ++idx) {
        int d = nidx[idx];
        int beg = doffs[d], end = doffs[d + 1];
        cnt += end - beg;
        for (int p = beg; p < end; ++p) {
            int eid = perm[p];
            int4 mm = wmeta[eid];
            float fx = __int_as_float(mm.x), fy = __int_as_float(mm.y), fz = __int_as_float(mm.z);
            int pack = mm.w;
            const float* base = &xW2[((size_t)(pack >> 5) * 27 + (pack & 31)) * 16 + o];
            float wxv[2] = {1.f - fx, fx}, wyv[2] = {1.f - fy, fy}, wzv[2] = {1.f - fz, fz};
#pragma unroll
            for (int j = 0; j < 8; ++j) {
                int cx = j & 1, cy = (j >> 1) & 1, cz = j >> 2;
                acc += wxv[cx] * wyv[cy] * wzv[cz] * base[KOFF[j] * 16];
            }
        }
    }
    M2[t] = acc / fmaxf((float)cnt, 1.f);
}

// ---- fallback reduce2 (no xW2 table; W2 blend from LDS columns) ----
__global__ __launch_bounds__(256) void reduce2_fb_kernel(
    const int* __restrict__ coff, const int* __restrict__ nidx,
    const int* __restrict__ doffs, const int* __restrict__ perm,
    const int4* __restrict__ wmeta, const float4* __restrict__ x1c4,
    const float* __restrict__ W2, float* __restrict__ M2, int N1)
{
    __shared__ float lw[27 * W2_STRIDE];
    for (int i = threadIdx.x; i < 27 * 128; i += 256)
        lw[(i >> 7) * W2_STRIDE + (i & 127)] = W2[i];
    __syncthreads();

    int t = blockIdx.x * 256 + threadIdx.x;
    if (t >= N1 * 16) return;
    int c = t >> 4, o = t & 15;
    float acc = 0.f;
    int cnt = 0;
    int cb = coff[c], ce = coff[c + 1];
    for (int idx = cb; idx < ce; ++idx) {
        int d = nidx[idx];
        int beg = doffs[d], end = doffs[d + 1];
        cnt += end - beg;
        for (int p = beg; p < end; ++p) {
            int eid = perm[p];
            int4 mm = wmeta[eid];
            float fx = __int_as_float(mm.x), fy = __int_as_float(mm.y), fz = __int_as_float(mm.z);
            int pack = mm.w;
            int s2 = pack >> 5, ibase = pack & 31;
            float4 xa = x1c4[2 * s2], xb = x1c4[2 * s2 + 1];
            float xr[8] = {xa.x, xa.y, xa.z, xa.w, xb.x, xb.y, xb.z, xb.w};
            float wxv[2] = {1.f - fx, fx}, wyv[2] = {1.f - fy, fy}, wzv[2] = {1.f - fz, fz};
#pragma unroll
            for (int j = 0; j < 8; ++j) {
                int cx = j & 1, cy = (j >> 1) & 1, cz = j >> 2;
                const float* Wk = &lw[(ibase + cx + 3 * cy + 9 * cz) * W2_STRIDE + o];
                float s = 0.f;
#pragma unroll
                for (int c8 = 0; c8 < 8; ++c8) s += xr[c8] * Wk[c8 * 16];
                acc += wxv[cx] * wyv[cy] * wzv[cz] * s;
            }
        }
    }
    M2[t] = acc / fmaxf((float)cnt, 1.f);
}

// ---- level 2 node + pool + graph sum (LDS-binned; tiny global atomic tail) ----
__global__ __launch_bounds__(256) void node2_kernel(
    const int* __restrict__ c2off, const int* __restrict__ n1idx,
    const float* __restrict__ M2, const float* __restrict__ x1c,
    const float* __restrict__ root2, const float* __restrict__ b2,
    const int* __restrict__ batch1,
    float* __restrict__ gsum, float* __restrict__ gcnt, int N2)
{
    __shared__ float ls[16 * 16];
    __shared__ float lc[16];
    for (int i = threadIdx.x; i < 256; i += 256) ls[i] = 0.f;
    if (threadIdx.x < 16) lc[threadIdx.x] = 0.f;
    __syncthreads();

    int c2 = blockIdx.x * 256 + threadIdx.x;
    if (c2 < N2) {
        int cb = c2off[c2], ce = c2off[c2 + 1];
        float hm[16];
#pragma unroll
        for (int o = 0; o < 16; ++o) hm[o] = -INFINITY;
        int bm = 0;
        for (int idx = cb; idx < ce; ++idx) {
            int n1 = n1idx[idx];
            const float4* xr4 = (const float4*)&x1c[(size_t)n1 * 8];
            float4 xa = xr4[0], xb = xr4[1];
            float xr[8] = {xa.x, xa.y, xa.z, xa.w, xb.x, xb.y, xb.z, xb.w};
#pragma unroll
            for (int o = 0; o < 16; ++o) {
                float v = M2[(size_t)n1 * 16 + o] + b2[o];
#pragma unroll
                for (int c8 = 0; c8 < 8; ++c8) v += xr[c8] * root2[c8 * 16 + o];
                hm[o] = fmaxf(hm[o], eluf(v));
            }
            bm = max(bm, batch1[n1]);
        }
        if (ce == cb) {
#pragma unroll
            for (int o = 0; o < 16; ++o) hm[o] = 0.f;  // empty -> zero row into graph 0
        }
#pragma unroll
        for (int o = 0; o < 16; ++o) atomicAdd(&ls[bm * 16 + o], hm[o]);
        atomicAdd(&lc[bm], 1.f);
    }
    __syncthreads();
    for (int i = threadIdx.x; i < 256; i += 256) unsafeAtomicAdd(&gsum[i], ls[i]);
    if (threadIdx.x < 16) unsafeAtomicAdd(&gcnt[threadIdx.x], lc[threadIdx.x]);
}

// ---- head ----
__global__ __launch_bounds__(256) void head_kernel(
    const float* __restrict__ gsum, const float* __restrict__ gcnt,
    const float* __restrict__ fc1_w, const float* __restrict__ fc1_b,
    const float* __restrict__ fc2_w, const float* __restrict__ fc2_b,
    float* __restrict__ out, int B)
{
    __shared__ float g[16 * 16];
    __shared__ float h1[16 * 64];
    int t = threadIdx.x;
    if (t < B * 16) {
        int b = t >> 4;
        g[t] = gsum[t] / fmaxf(gcnt[b], 1.f);
    }
    __syncthreads();
    for (int j = t; j < B * 64; j += 256) {
        int b = j >> 6, jj = j & 63;
        float s = fc1_b[jj];
#pragma unroll
        for (int c = 0; c < 16; ++c) s += g[b * 16 + c] * fc1_w[c * 64 + jj];
        h1[j] = eluf(s);
    }
    __syncthreads();
    if (t < B) {
        float s = fc2_b[0];
#pragma unroll
        for (int j = 0; j < 64; ++j) s += h1[t * 64 + j] * fc2_w[j];
        out[t] = eluf(s);
    }
}

extern "C" void kernel_launch(void* const* d_in, const int* in_sizes, int n_in,
                              void* d_out, int out_size, void* d_ws, size_t ws_size,
                              hipStream_t stream)
{
    const float* x        = (const float*)d_in[0];
    const int*   ei       = (const int*)  d_in[1];
    const float* attr     = (const float*)d_in[2];
    const int*   batch    = (const int*)  d_in[3];
    const int*   cluster1 = (const int*)  d_in[4];
    const int*   cluster2 = (const int*)  d_in[5];
    const float* W1       = (const float*)d_in[6];
    const float* root1    = (const float*)d_in[7];
    const float* b1       = (const float*)d_in[8];
    const float* W2       = (const float*)d_in[9];
    const float* root2    = (const float*)d_in[10];
    const float* b2       = (const float*)d_in[11];
    const float* fc1_w    = (const float*)d_in[12];
    const float* fc1_b    = (const float*)d_in[13];
    const float* fc2_w    = (const float*)d_in[14];
    const float* fc2_b    = (const float*)d_in[15];

    const int N  = in_sizes[0] / 2;
    const int E  = in_sizes[1] / 2;
    const int N1 = in_sizes[5];
    const int N2 = N1 / 2;
    const int B  = out_size;

    const int nb0 = (N  + SCAN_CHUNK - 1) / SCAN_CHUNK;
    const int nb1 = (N1 + SCAN_CHUNK - 1) / SCAN_CHUNK;
    const int nb2 = (N2 + SCAN_CHUNK - 1) / SCAN_CHUNK;

    int* wi = (int*)d_ws;
    size_t off = 0;
    auto alloc = [&](size_t n, size_t align = 1) {
        off = (off + align - 1) & ~(align - 1);
        size_t r = off; off += n; return r;
    };
    // zero-init region
    int*   deg    = wi + alloc(N);
    int*   cdeg   = wi + alloc(N1);
    int*   c2deg  = wi + alloc(N2);
    float* gsum   = (float*)(wi + alloc((size_t)B * 16));
    float* gcnt   = (float*)(wi + alloc(B));
    const size_t zcount = off;
    // rest
    int*   doffs  = wi + alloc(N + 1);
    int*   coff   = wi + alloc(N1 + 1);
    int*   c2off  = wi + alloc(N2 + 1);
    int*   auxA   = wi + alloc(nb0);
    int*   auxB   = wi + alloc(nb1);
    int*   auxC   = wi + alloc(nb2);
    int*   rank   = wi + alloc(E);
    int*   rankC  = wi + alloc(N);
    int*   rank2  = wi + alloc(N1);
    int*   perm   = wi + alloc(E);
    int*   nidx   = wi + alloc(N);
    int*   n1idx  = wi + alloc(N1);
    int4*  wmeta  = (int4*)(wi + alloc((size_t)E * 4, 4));
    float* msg1   = (float*)(wi + alloc((size_t)E * 8, 4));
    float* M1     = (float*)(wi + alloc((size_t)N * 8, 4));
    float* x1c    = (float*)(wi + alloc((size_t)N1 * 8, 4));
    int*   batch1 = wi + alloc(N1);
    float* M2     = (float*)(wi + alloc((size_t)N1 * 16, 4));
    float* xW2    = (float*)(wi + alloc((size_t)N1 * 27 * 16, 4));
    const bool use_xw2 = (off * sizeof(int) <= ws_size);

    hipMemsetAsync(d_ws, 0, zcount * sizeof(int), stream);

    const int eb = (E + 255) / 256;
    hist_kernel<<<eb, 256, 0, stream>>>(ei, cluster1, cluster2,
                                        deg, rank, cdeg, rankC, c2deg, rank2, E, N, N1);
    scan_a<<<nb0 + nb1 + nb2, 256, 0, stream>>>(deg, doffs, auxA, N, nb0,
                                                cdeg, coff, auxB, N1, nb1,
                                                c2deg, c2off, auxC, N2);
    scan_b<<<3, 64, 0, stream>>>(auxA, nb0, doffs, N,
                                 auxB, nb1, coff, N1,
                                 auxC, nb2, c2off, N2);
    scan_c<<<nb0 + nb1 + nb2, 256, 0, stream>>>(doffs, auxA, N, nb0,
                                                coff, auxB, N1, nb1,
                                                c2off, auxC, N2);
    scatA_kernel<<<eb, 256, 0, stream>>>(ei, attr, cluster1, cluster2,
                                         (const float2*)x, W1,
                                         doffs, rank, coff, rankC, c2off, rank2,
                                         perm, nidx, n1idx, msg1, wmeta, E, N, N1);
    reduce1_kernel<<<(N * 8 + 255) / 256, 256, 0, stream>>>(perm, doffs, msg1, M1, N);
    node1_gather<<<(N1 + 255) / 256, 256, 0, stream>>>(
        coff, nidx, M1, (const float2*)x, root1, b1, batch, x1c, batch1, N1);
    if (use_xw2) {
        xw2_kernel<<<(N1 * 27 + 255) / 256, 256, 0, stream>>>(
            (const float4*)x1c, W2, xW2, N1);
        reduce2_kernel<<<(N1 * 16 + 255) / 256, 256, 0, stream>>>(
            coff, nidx, doffs, perm, wmeta, xW2, M2, N1);
    } else {
        reduce2_fb_kernel<<<(N1 * 16 + 255) / 256, 256, 0, stream>>>(
            coff, nidx, doffs, perm, wmeta, (const float4*)x1c, W2, M2, N1);
    }
    node2_kernel<<<(N2 + 255) / 256, 256, 0, stream>>>(
        c2off, n1idx, M2, x1c, root2, b2, batch1, gsum, gcnt, N2);
    head_kernel<<<1, 256, 0, stream>>>(gsum, gcnt, fc1_w, fc1_b, fc2_w, fc2_b,
                                       (float*)d_out, B);
}

// Round 4
// 465.862 us; speedup vs baseline: 4.4955x; 1.2555x over previous
//
#include <hip/hip_runtime.h>
#include <hip/hip_fp16.h>
#include <math.h>

// ---------------------------------------------------------------------------
// Net_75505525064500 — round 4.
// R3 evidence: reduce2 bound by random 64-B line gathers from the 69 MB fp32
//   xW2 table (FETCH 611 MB = E x 8 x 64 B; 2.34 TB/s miss-path; 261 us).
// R4: (a) half2 pair-packed table: the 8 trilinear corners = 4 x-adjacent row
//   pairs; store pair rows interleaved as half2 so one aligned 64-B line per
//   pair serves all 16 channels -> 4 loads/edge, 256 B/edge (was 8 / 512 B).
//   (b) scatA writes msg1/wmeta directly at CSR slot p (no perm array);
//   reduce1/reduce2 stream them sequentially. (c) node1 channel-parallel.
// Sizes: N=80000 (Cin=2), E=1280000, N1=40000 (C=8), N2=20000 (C=16), B=16.
// ---------------------------------------------------------------------------

__device__ __forceinline__ float eluf(float x) {
    return x > 0.f ? x : (expf(x) - 1.f);
}

#define W1_STRIDE 20
#define W2_STRIDE 132  // measured 0 LDS bank conflicts (R1-R3)

// ---- phase 1: histograms + within-bin ranks (the only big atomic pass) ----
__global__ __launch_bounds__(256) void hist_kernel(
    const int* __restrict__ ei, const int* __restrict__ cluster1,
    const int* __restrict__ cluster2,
    int* __restrict__ deg, int* __restrict__ rank,
    int* __restrict__ cdeg, int* __restrict__ rankC,
    int* __restrict__ c2deg, int* __restrict__ rank2,
    int E, int N, int N1)
{
    int i = blockIdx.x * 256 + threadIdx.x;
    if (i < E)  rank[i]  = atomicAdd(&deg[ei[E + i]], 1);
    if (i < N)  rankC[i] = atomicAdd(&cdeg[cluster1[i]], 1);
    if (i < N1) rank2[i] = atomicAdd(&c2deg[cluster2[i]], 1);
}

// ---- phase 2: two-level exclusive scan, 3 arrays per launch ----
#define SCAN_CHUNK 4096

__global__ __launch_bounds__(256) void scan_a(
    const int* __restrict__ in0, int* __restrict__ out0, int* __restrict__ aux0, int L0, int nb0,
    const int* __restrict__ in1, int* __restrict__ out1, int* __restrict__ aux1, int L1, int nb1,
    const int* __restrict__ in2, int* __restrict__ out2, int* __restrict__ aux2, int L2)
{
    int b = blockIdx.x;
    const int* in; int* out; int* aux; int L;
    if (b < nb0)            { in = in0; out = out0; aux = aux0; L = L0; }
    else if (b < nb0 + nb1) { b -= nb0; in = in1; out = out1; aux = aux1; L = L1; }
    else                    { b -= nb0 + nb1; in = in2; out = out2; aux = aux2; L = L2; }

    __shared__ int ls[256];
    int t = threadIdx.x;
    int base = b * SCAN_CHUNK + t * 16;
    int v[16];
    int s = 0;
#pragma unroll
    for (int j = 0; j < 16; ++j) {
        int val = (base + j < L) ? in[base + j] : 0;
        v[j] = s;
        s += val;
    }
    ls[t] = s;
    __syncthreads();
    for (int off = 1; off < 256; off <<= 1) {
        int tv = (t >= off) ? ls[t - off] : 0;
        __syncthreads();
        ls[t] += tv;
        __syncthreads();
    }
    int excl = ls[t] - s;
#pragma unroll
    for (int j = 0; j < 16; ++j)
        if (base + j < L) out[base + j] = excl + v[j];
    if (t == 255) aux[b] = ls[255];
}

__global__ __launch_bounds__(64) void scan_b(
    int* __restrict__ aux0, int nb0, int* __restrict__ off0, int L0,
    int* __restrict__ aux1, int nb1, int* __restrict__ off1, int L1,
    int* __restrict__ aux2, int nb2, int* __restrict__ off2, int L2)
{
    if (threadIdx.x != 0) return;
    int* aux; int nb; int* off; int L;
    if (blockIdx.x == 0)      { aux = aux0; nb = nb0; off = off0; L = L0; }
    else if (blockIdx.x == 1) { aux = aux1; nb = nb1; off = off1; L = L1; }
    else                      { aux = aux2; nb = nb2; off = off2; L = L2; }
    int run = 0;
    for (int j = 0; j < nb; ++j) { int tv = aux[j]; aux[j] = run; run += tv; }
    off[L] = run;
}

__global__ __launch_bounds__(256) void scan_c(
    int* __restrict__ out0, const int* __restrict__ aux0, int L0, int nb0,
    int* __restrict__ out1, const int* __restrict__ aux1, int L1, int nb1,
    int* __restrict__ out2, const int* __restrict__ aux2, int L2)
{
    int b = blockIdx.x;
    int* out; const int* aux; int L;
    if (b < nb0)            { out = out0; aux = aux0; L = L0; }
    else if (b < nb0 + nb1) { b -= nb0; out = out1; aux = aux1; L = L1; }
    else                    { b -= nb0 + nb1; out = out2; aux = aux2; L = L2; }
    int add = aux[b];
    int base = b * SCAN_CHUNK + threadIdx.x * 16;
#pragma unroll
    for (int j = 0; j < 16; ++j)
        if (base + j < L) out[base + j] += add;
}

// ---- phase 3 (fused): edge-parallel msg1/meta computed coalesced, written
//      directly at CSR slot p = doffs[dst]+rank (the only random writes) ----
__global__ __launch_bounds__(256) void scatA_kernel(
    const int* __restrict__ ei, const float* __restrict__ attr,
    const int* __restrict__ cluster1, const int* __restrict__ cluster2,
    const float2* __restrict__ x, const float* __restrict__ W1,
    const int* __restrict__ doffs, const int* __restrict__ rank,
    const int* __restrict__ coff, const int* __restrict__ rankC,
    const int* __restrict__ c2off, const int* __restrict__ rank2,
    int* __restrict__ nidx, int* __restrict__ n1idx,
    float* __restrict__ msg1, int4* __restrict__ wmeta,
    int E, int N, int N1)
{
    __shared__ float lw[27 * W1_STRIDE];
    for (int i = threadIdx.x; i < 27 * 16; i += 256)
        lw[(i >> 4) * W1_STRIDE + (i & 15)] = W1[i];
    __syncthreads();

    int i = blockIdx.x * 256 + threadIdx.x;
    if (i < E) {
        int s = ei[i], d = ei[E + i];
        int p = doffs[d] + rank[i];

        float vx = attr[3 * i] * 2.f, vy = attr[3 * i + 1] * 2.f, vz = attr[3 * i + 2] * 2.f;
        float ix = fmaxf(fminf(floorf(vx), 1.f), 0.f);
        float iy = fmaxf(fminf(floorf(vy), 1.f), 0.f);
        float iz = fmaxf(fminf(floorf(vz), 1.f), 0.f);
        float fx = vx - ix, fy = vy - iy, fz = vz - iz;
        int ixi = (int)ix, iyi = (int)iy, izi = (int)iz;
        int ibase = ixi + 3 * iyi + 9 * izi;

        float2 xv = x[s];
        float wxv[2] = {1.f - fx, fx}, wyv[2] = {1.f - fy, fy}, wzv[2] = {1.f - fz, fz};
        float m[8];
#pragma unroll
        for (int o = 0; o < 8; ++o) m[o] = 0.f;
#pragma unroll
        for (int j = 0; j < 8; ++j) {
            int cx = j & 1, cy = (j >> 1) & 1, cz = j >> 2;
            float w = wxv[cx] * wyv[cy] * wzv[cz];
            const float* Wk = &lw[(ibase + cx + 3 * cy + 9 * cz) * W1_STRIDE];
            float a = w * xv.x, bb = w * xv.y;
            const float4 wa0 = *(const float4*)&Wk[0];
            const float4 wa1 = *(const float4*)&Wk[4];
            const float4 wb0 = *(const float4*)&Wk[8];
            const float4 wb1 = *(const float4*)&Wk[12];
            m[0] += a * wa0.x + bb * wb0.x;
            m[1] += a * wa0.y + bb * wb0.y;
            m[2] += a * wa0.z + bb * wb0.z;
            m[3] += a * wa0.w + bb * wb0.w;
            m[4] += a * wa1.x + bb * wb1.x;
            m[5] += a * wa1.y + bb * wb1.y;
            m[6] += a * wa1.z + bb * wb1.z;
            m[7] += a * wa1.w + bb * wb1.w;
        }
        float4* mo = (float4*)&msg1[(size_t)p * 8];
        mo[0] = make_float4(m[0], m[1], m[2], m[3]);
        mo[1] = make_float4(m[4], m[5], m[6], m[7]);
        // pack = s2<<3 | iz0<<2 | iy0<<1 | ix   (s2 < 2^26)
        int pack = (cluster1[s] << 3) | (izi << 2) | (iyi << 1) | ixi;
        wmeta[p] = make_int4(__float_as_int(fx), __float_as_int(fy), __float_as_int(fz), pack);
    }
    if (i < N)  nidx[coff[cluster1[i]] + rankC[i]] = i;
    if (i < N1) n1idx[c2off[cluster2[i]] + rank2[i]] = i;
}

// ---- reduce msg1 by dst: thread per (dst, channel); msg1 now CSR-ordered ----
__global__ __launch_bounds__(256) void reduce1_kernel(
    const int* __restrict__ doffs, const float* __restrict__ msg1,
    float* __restrict__ M1, int N)
{
    int t = blockIdx.x * 256 + threadIdx.x;
    if (t >= N * 8) return;
    int d = t >> 3, ch = t & 7;
    int beg = doffs[d], end = doffs[d + 1];
    float acc = 0.f;
    for (int p = beg; p < end; ++p)
        acc += msg1[(size_t)p * 8 + ch];  // sequential streaming
    M1[t] = acc / fmaxf((float)(end - beg), 1.f);
}

// ---- level 1 pool: thread per (cluster, channel) gather-max ----
__global__ __launch_bounds__(256) void node1_gather(
    const int* __restrict__ coff, const int* __restrict__ nidx,
    const float* __restrict__ M1, const float2* __restrict__ x,
    const float* __restrict__ root1, const float* __restrict__ b1,
    const int* __restrict__ batch,
    float* __restrict__ x1c, int* __restrict__ batch1, int N1)
{
    int t = blockIdx.x * 256 + threadIdx.x;
    if (t >= N1 * 8) return;
    int c = t >> 3, o = t & 7;
    int cb = coff[c], ce = coff[c + 1];
    float r0 = root1[o], r1 = root1[8 + o], bo = b1[o];
    float hm = -INFINITY;
    int bm = 0;
    for (int idx = cb; idx < ce; ++idx) {
        int d = nidx[idx];
        float2 xv = x[d];
        float h = eluf(M1[(size_t)d * 8 + o] + xv.x * r0 + xv.y * r1 + bo);
        hm = fmaxf(hm, h);
        bm = max(bm, batch[d]);
    }
    if (ce == cb) hm = 0.f;
    x1c[t] = hm;
    if (o == 0) batch1[c] = bm;
}

// ---- xW2 pair table: slot s=(iz*3+iy)*2+kx0 -> half2(rowk[o], rowk1[o]) ----
// One 64-B line per (s2, slot) serves all 16 channels of both x-corners.
__global__ __launch_bounds__(256) void xw2p_kernel(
    const float4* __restrict__ x1c4, const float* __restrict__ W2,
    unsigned* __restrict__ xW2p, int N1)
{
    __shared__ float lw[27 * W2_STRIDE];
    for (int i = threadIdx.x; i < 27 * 128; i += 256)
        lw[(i >> 7) * W2_STRIDE + (i & 127)] = W2[i];
    __syncthreads();

    int t = blockIdx.x * 256 + threadIdx.x;
    if (t >= N1 * 18) return;
    int s2 = t / 18;
    int s = t - 18 * s2;
    int kx0 = s & 1, rc = s >> 1;
    int iy = rc % 3, iz = rc / 3;
    int k0 = iz * 9 + iy * 3 + kx0;

    float4 xa = x1c4[2 * s2], xb = x1c4[2 * s2 + 1];
    float xr[8] = {xa.x, xa.y, xa.z, xa.w, xb.x, xb.y, xb.z, xb.w};

    float v0[16], v1[16];
#pragma unroll
    for (int o = 0; o < 16; ++o) { v0[o] = 0.f; v1[o] = 0.f; }
    const float* Wk0 = &lw[k0 * W2_STRIDE];
    const float* Wk1 = &lw[(k0 + 1) * W2_STRIDE];
#pragma unroll
    for (int c = 0; c < 8; ++c) {
        float a = xr[c];
#pragma unroll
        for (int q = 0; q < 4; ++q) {
            float4 w0 = *(const float4*)&Wk0[c * 16 + 4 * q];
            float4 w1 = *(const float4*)&Wk1[c * 16 + 4 * q];
            v0[4 * q]     += a * w0.x; v0[4 * q + 1] += a * w0.y;
            v0[4 * q + 2] += a * w0.z; v0[4 * q + 3] += a * w0.w;
            v1[4 * q]     += a * w1.x; v1[4 * q + 1] += a * w1.y;
            v1[4 * q + 2] += a * w1.z; v1[4 * q + 3] += a * w1.w;
        }
    }
    unsigned* out = &xW2p[(size_t)t * 16];
#pragma unroll
    for (int o = 0; o < 16; ++o) {
        __half2 h2 = __floats2half2_rn(v0[o], v1[o]);
        out[o] = *(unsigned*)&h2;
    }
}

// ---- level 2 reduce: thread per (cluster, channel); 4 pair-line gathers/edge ----
__global__ __launch_bounds__(256) void reduce2_kernel(
    const int* __restrict__ coff, const int* __restrict__ nidx,
    const int* __restrict__ doffs, const int4* __restrict__ wmeta,
    const unsigned* __restrict__ xW2p, float* __restrict__ M2, int N1)
{
    int t = blockIdx.x * 256 + threadIdx.x;
    if (t >= N1 * 16) return;
    int c = t >> 4, o = t & 15;
    float acc = 0.f;
    int cnt = 0;
    int cb = coff[c], ce = coff[c + 1];
    for (int idx = cb; idx < ce; ++idx) {
        int d = nidx[idx];
        int beg = doffs[d], end = doffs[d + 1];
        cnt += end - beg;
        for (int p = beg; p < end; ++p) {
            int4 mm = wmeta[p];  // sequential stream
            float fx = __int_as_float(mm.x), fy = __int_as_float(mm.y), fz = __int_as_float(mm.z);
            int pack = mm.w;
            int s2 = pack >> 3, iz0 = (pack >> 2) & 1, iy0 = (pack >> 1) & 1, ixb = pack & 1;
            const unsigned* base = &xW2p[(size_t)s2 * 288 + o];  // 18 slots * 16
            float wx0 = 1.f - fx, wy0 = 1.f - fy, wz0 = 1.f - fz;
#pragma unroll
            for (int j = 0; j < 4; ++j) {
                int cy = j & 1, cz = j >> 1;
                int slot = ((iz0 + cz) * 3 + (iy0 + cy)) * 2 + ixb;
                unsigned v = base[slot * 16];
                float2 f2 = __half22float2(*(__half2*)&v);
                float wyz = (cy ? fy : wy0) * (cz ? fz : wz0);
                acc += wyz * (wx0 * f2.x + fx * f2.y);
            }
        }
    }
    M2[t] = acc / fmaxf((float)cnt, 1.f);
}

// ---- fallback (if ws too small for table): blend from LDS W2 columns ----
__global__ __launch_bounds__(256) void reduce2_fb_kernel(
    const int* __restrict__ coff, const int* __restrict__ nidx,
    const int* __restrict__ doffs, const int4* __restrict__ wmeta,
    const float4* __restrict__ x1c4, const float* __restrict__ W2,
    float* __restrict__ M2, int N1)
{
    __shared__ float lw[27 * W2_STRIDE];
    for (int i = threadIdx.x; i < 27 * 128; i += 256)
        lw[(i >> 7) * W2_STRIDE + (i & 127)] = W2[i];
    __syncthreads();

    int t = blockIdx.x * 256 + threadIdx.x;
    if (t >= N1 * 16) return;
    int c = t >> 4, o = t & 15;
    float acc = 0.f;
    int cnt = 0;
    int cb = coff[c], ce = coff[c + 1];
    for (int idx = cb; idx < ce; ++idx) {
        int d = nidx[idx];
        int beg = doffs[d], end = doffs[d + 1];
        cnt += end - beg;
        for (int p = beg; p < end; ++p) {
            int4 mm = wmeta[p];
            float fx = __int_as_float(mm.x), fy = __int_as_float(mm.y), fz = __int_as_float(mm.z);
            int pack = mm.w;
            int s2 = pack >> 3, iz0 = (pack >> 2) & 1, iy0 = (pack >> 1) & 1, ixb = pack & 1;
            int ibase = ixb + 3 * iy0 + 9 * iz0;
            float4 xa = x1c4[2 * s2], xb = x1c4[2 * s2 + 1];
            float xr[8] = {xa.x, xa.y, xa.z, xa.w, xb.x, xb.y, xb.z, xb.w};
            float wxv[2] = {1.f - fx, fx}, wyv[2] = {1.f - fy, fy}, wzv[2] = {1.f - fz, fz};
#pragma unroll
            for (int j = 0; j < 8; ++j) {
                int cx = j & 1, cy = (j >> 1) & 1, cz = j >> 2;
                const float* Wk = &lw[(ibase + cx + 3 * cy + 9 * cz) * W2_STRIDE + o];
                float s = 0.f;
#pragma unroll
                for (int c8 = 0; c8 < 8; ++c8) s += xr[c8] * Wk[c8 * 16];
                acc += wxv[cx] * wyv[cy] * wzv[cz] * s;
            }
        }
    }
    M2[t] = acc / fmaxf((float)cnt, 1.f);
}

// ---- level 2 node + pool + graph sum (LDS-binned; tiny global atomic tail) ----
__global__ __launch_bounds__(256) void node2_kernel(
    const int* __restrict__ c2off, const int* __restrict__ n1idx,
    const float* __restrict__ M2, const float* __restrict__ x1c,
    const float* __restrict__ root2, const float* __restrict__ b2,
    const int* __restrict__ batch1,
    float* __restrict__ gsum, float* __restrict__ gcnt, int N2)
{
    __shared__ float ls[16 * 16];
    __shared__ float lc[16];
    for (int i = threadIdx.x; i < 256; i += 256) ls[i] = 0.f;
    if (threadIdx.x < 16) lc[threadIdx.x] = 0.f;
    __syncthreads();

    int c2 = blockIdx.x * 256 + threadIdx.x;
    if (c2 < N2) {
        int cb = c2off[c2], ce = c2off[c2 + 1];
        float hm[16];
#pragma unroll
        for (int o = 0; o < 16; ++o) hm[o] = -INFINITY;
        int bm = 0;
        for (int idx = cb; idx < ce; ++idx) {
            int n1 = n1idx[idx];
            const float4* xr4 = (const float4*)&x1c[(size_t)n1 * 8];
            float4 xa = xr4[0], xb = xr4[1];
            float xr[8] = {xa.x, xa.y, xa.z, xa.w, xb.x, xb.y, xb.z, xb.w};
#pragma unroll
            for (int o = 0; o < 16; ++o) {
                float v = M2[(size_t)n1 * 16 + o] + b2[o];
#pragma unroll
                for (int c8 = 0; c8 < 8; ++c8) v += xr[c8] * root2[c8 * 16 + o];
                hm[o] = fmaxf(hm[o], eluf(v));
            }
            bm = max(bm, batch1[n1]);
        }
        if (ce == cb) {
#pragma unroll
            for (int o = 0; o < 16; ++o) hm[o] = 0.f;
        }
#pragma unroll
        for (int o = 0; o < 16; ++o) atomicAdd(&ls[bm * 16 + o], hm[o]);
        atomicAdd(&lc[bm], 1.f);
    }
    __syncthreads();
    for (int i = threadIdx.x; i < 256; i += 256) unsafeAtomicAdd(&gsum[i], ls[i]);
    if (threadIdx.x < 16) unsafeAtomicAdd(&gcnt[threadIdx.x], lc[threadIdx.x]);
}

// ---- head ----
__global__ __launch_bounds__(256) void head_kernel(
    const float* __restrict__ gsum, const float* __restrict__ gcnt,
    const float* __restrict__ fc1_w, const float* __restrict__ fc1_b,
    const float* __restrict__ fc2_w, const float* __restrict__ fc2_b,
    float* __restrict__ out, int B)
{
    __shared__ float g[16 * 16];
    __shared__ float h1[16 * 64];
    int t = threadIdx.x;
    if (t < B * 16) {
        int b = t >> 4;
        g[t] = gsum[t] / fmaxf(gcnt[b], 1.f);
    }
    __syncthreads();
    for (int j = t; j < B * 64; j += 256) {
        int b = j >> 6, jj = j & 63;
        float s = fc1_b[jj];
#pragma unroll
        for (int c = 0; c < 16; ++c) s += g[b * 16 + c] * fc1_w[c * 64 + jj];
        h1[j] = eluf(s);
    }
    __syncthreads();
    if (t < B) {
        float s = fc2_b[0];
#pragma unroll
        for (int j = 0; j < 64; ++j) s += h1[t * 64 + j] * fc2_w[j];
        out[t] = eluf(s);
    }
}

extern "C" void kernel_launch(void* const* d_in, const int* in_sizes, int n_in,
                              void* d_out, int out_size, void* d_ws, size_t ws_size,
                              hipStream_t stream)
{
    const float* x        = (const float*)d_in[0];
    const int*   ei       = (const int*)  d_in[1];
    const float* attr     = (const float*)d_in[2];
    const int*   batch    = (const int*)  d_in[3];
    const int*   cluster1 = (const int*)  d_in[4];
    const int*   cluster2 = (const int*)  d_in[5];
    const float* W1       = (const float*)d_in[6];
    const float* root1    = (const float*)d_in[7];
    const float* b1       = (const float*)d_in[8];
    const float* W2       = (const float*)d_in[9];
    const float* root2    = (const float*)d_in[10];
    const float* b2       = (const float*)d_in[11];
    const float* fc1_w    = (const float*)d_in[12];
    const float* fc1_b    = (const float*)d_in[13];
    const float* fc2_w    = (const float*)d_in[14];
    const float* fc2_b    = (const float*)d_in[15];

    const int N  = in_sizes[0] / 2;
    const int E  = in_sizes[1] / 2;
    const int N1 = in_sizes[5];
    const int N2 = N1 / 2;
    const int B  = out_size;

    const int nb0 = (N  + SCAN_CHUNK - 1) / SCAN_CHUNK;
    const int nb1 = (N1 + SCAN_CHUNK - 1) / SCAN_CHUNK;
    const int nb2 = (N2 + SCAN_CHUNK - 1) / SCAN_CHUNK;

    int* wi = (int*)d_ws;
    size_t off = 0;
    auto alloc = [&](size_t n, size_t align = 1) {
        off = (off + align - 1) & ~(align - 1);
        size_t r = off; off += n; return r;
    };
    // zero-init region
    int*   deg    = wi + alloc(N);
    int*   cdeg   = wi + alloc(N1);
    int*   c2deg  = wi + alloc(N2);
    float* gsum   = (float*)(wi + alloc((size_t)B * 16));
    float* gcnt   = (float*)(wi + alloc(B));
    const size_t zcount = off;
    // rest (fully overwritten before read)
    int*   doffs  = wi + alloc(N + 1);
    int*   coff   = wi + alloc(N1 + 1);
    int*   c2off  = wi + alloc(N2 + 1);
    int*   auxA   = wi + alloc(nb0);
    int*   auxB   = wi + alloc(nb1);
    int*   auxC   = wi + alloc(nb2);
    int*   rank   = wi + alloc(E);
    int*   rankC  = wi + alloc(N);
    int*   rank2  = wi + alloc(N1);
    int*   nidx   = wi + alloc(N);
    int*   n1idx  = wi + alloc(N1);
    int4*  wmeta  = (int4*)(wi + alloc((size_t)E * 4, 4));
    float* msg1   = (float*)(wi + alloc((size_t)E * 8, 8));
    float* M1     = (float*)(wi + alloc((size_t)N * 8, 4));
    float* x1c    = (float*)(wi + alloc((size_t)N1 * 8, 4));
    int*   batch1 = wi + alloc(N1);
    float* M2     = (float*)(wi + alloc((size_t)N1 * 16, 4));
    unsigned* xW2p = (unsigned*)(wi + alloc((size_t)N1 * 18 * 16, 16));  // 64-B aligned lines
    const bool use_xw2 = (off * sizeof(int) <= ws_size);

    hipMemsetAsync(d_ws, 0, zcount * sizeof(int), stream);

    const int eb = (E + 255) / 256;
    hist_kernel<<<eb, 256, 0, stream>>>(ei, cluster1, cluster2,
                                        deg, rank, cdeg, rankC, c2deg, rank2, E, N, N1);
    scan_a<<<nb0 + nb1 + nb2, 256, 0, stream>>>(deg, doffs, auxA, N, nb0,
                                                cdeg, coff, auxB, N1, nb1,
                                                c2deg, c2off, auxC, N2);
    scan_b<<<3, 64, 0, stream>>>(auxA, nb0, doffs, N,
                                 auxB, nb1, coff, N1,
                                 auxC, nb2, c2off, N2);
    scan_c<<<nb0 + nb1 + nb2, 256, 0, stream>>>(doffs, auxA, N, nb0,
                                                coff, auxB, N1, nb1,
                                                c2off, auxC, N2);
    scatA_kernel<<<eb, 256, 0, stream>>>(ei, attr, cluster1, cluster2,
                                         (const float2*)x, W1,
                                         doffs, rank, coff, rankC, c2off, rank2,
                                         nidx, n1idx, msg1, wmeta, E, N, N1);
    reduce1_kernel<<<(N * 8 + 255) / 256, 256, 0, stream>>>(doffs, msg1, M1, N);
    node1_gather<<<(N1 * 8 + 255) / 256, 256, 0, stream>>>(
        coff, nidx, M1, (const float2*)x, root1, b1, batch, x1c, batch1, N1);
    if (use_xw2) {
        xw2p_kernel<<<(N1 * 18 + 255) / 256, 256, 0, stream>>>(
            (const float4*)x1c, W2, xW2p, N1);
        reduce2_kernel<<<(N1 * 16 + 255) / 256, 256, 0, stream>>>(
            coff, nidx, doffs, wmeta, xW2p, M2, N1);
    } else {
        reduce2_fb_kernel<<<(N1 * 16 + 255) / 256, 256, 0, stream>>>(
            coff, nidx, doffs, wmeta, (const float4*)x1c, W2, M2, N1);
    }
    node2_kernel<<<(N2 + 255) / 256, 256, 0, stream>>>(
        c2off, n1idx, M2, x1c, root2, b2, batch1, gsum, gcnt, N2);
    head_kernel<<<1, 256, 0, stream>>>(gsum, gcnt, fc1_w, fc1_b, fc2_w, fc2_b,
                                       (float*)d_out, B);
}

// Round 5
// 458.553 us; speedup vs baseline: 4.5672x; 1.0159x over previous
//
#include <hip/hip_runtime.h>
#include <hip/hip_fp16.h>
#include <math.h>

// ---------------------------------------------------------------------------
// Net_75505525064500 — round 5.
// R4 evidence: reduce2 moves ~30-36 random 64-B lines/us regardless of bytes
//   (R3: 9.4M lines/261us, R4: 4.6M/161us) -> bound by random-region touches.
// R5: corner-expanded half table tab[s2][slot(ix,iy,iz)][ch][8 corners]
//   (2048 B/s2, 82 MB streamed once) -> ONE contiguous 256-B touch per edge
//   (16 ch-lanes x dwordx4). Also: meta-only scatter (16 B/edge, msg1 dead),
//   level-1 reduce+pool fused (node1L recomputes messages from meta).
// Sizes: N=80000 (Cin=2), E=1280000, N1=40000 (C=8), N2=20000 (C=16), B=16.
// ---------------------------------------------------------------------------

__device__ __forceinline__ float eluf(float x) {
    return x > 0.f ? x : (expf(x) - 1.f);
}

__device__ __forceinline__ float hlo(int v) {
    __half2 h; *(int*)&h = v; return __low2float(h);
}
__device__ __forceinline__ float hhi(int v) {
    __half2 h; *(int*)&h = v; return __high2float(h);
}

#define W1_STRIDE 20
#define W2_STRIDE 132  // measured 0 LDS bank conflicts (R1-R4)

// meta per edge (int4):
//   x = s2 | slot<<16        (s2 < 65536, slot = ix + 2iy + 4iz)
//   y = src | ibase<<17      (src < 2^17, ibase = ix + 3iy + 9iz)
//   z = half(fx) | half(fy)<<16
//   w = half(fz)

// ---- phase 1: histograms + within-bin ranks ----
__global__ __launch_bounds__(256) void hist_kernel(
    const int* __restrict__ ei, const int* __restrict__ cluster1,
    const int* __restrict__ cluster2,
    int* __restrict__ deg, int* __restrict__ rank,
    int* __restrict__ cdeg, int* __restrict__ rankC,
    int* __restrict__ c2deg, int* __restrict__ rank2,
    int E, int N, int N1)
{
    int i = blockIdx.x * 256 + threadIdx.x;
    if (i < E)  rank[i]  = atomicAdd(&deg[ei[E + i]], 1);
    if (i < N)  rankC[i] = atomicAdd(&cdeg[cluster1[i]], 1);
    if (i < N1) rank2[i] = atomicAdd(&c2deg[cluster2[i]], 1);
}

// ---- phase 2: two-level exclusive scan, 3 arrays per launch ----
#define SCAN_CHUNK 4096

__global__ __launch_bounds__(256) void scan_a(
    const int* __restrict__ in0, int* __restrict__ out0, int* __restrict__ aux0, int L0, int nb0,
    const int* __restrict__ in1, int* __restrict__ out1, int* __restrict__ aux1, int L1, int nb1,
    const int* __restrict__ in2, int* __restrict__ out2, int* __restrict__ aux2, int L2)
{
    int b = blockIdx.x;
    const int* in; int* out; int* aux; int L;
    if (b < nb0)            { in = in0; out = out0; aux = aux0; L = L0; }
    else if (b < nb0 + nb1) { b -= nb0; in = in1; out = out1; aux = aux1; L = L1; }
    else                    { b -= nb0 + nb1; in = in2; out = out2; aux = aux2; L = L2; }

    __shared__ int ls[256];
    int t = threadIdx.x;
    int base = b * SCAN_CHUNK + t * 16;
    int v[16];
    int s = 0;
#pragma unroll
    for (int j = 0; j < 16; ++j) {
        int val = (base + j < L) ? in[base + j] : 0;
        v[j] = s;
        s += val;
    }
    ls[t] = s;
    __syncthreads();
    for (int off = 1; off < 256; off <<= 1) {
        int tv = (t >= off) ? ls[t - off] : 0;
        __syncthreads();
        ls[t] += tv;
        __syncthreads();
    }
    int excl = ls[t] - s;
#pragma unroll
    for (int j = 0; j < 16; ++j)
        if (base + j < L) out[base + j] = excl + v[j];
    if (t == 255) aux[b] = ls[255];
}

__global__ __launch_bounds__(64) void scan_b(
    int* __restrict__ aux0, int nb0, int* __restrict__ off0, int L0,
    int* __restrict__ aux1, int nb1, int* __restrict__ off1, int L1,
    int* __restrict__ aux2, int nb2, int* __restrict__ off2, int L2)
{
    if (threadIdx.x != 0) return;
    int* aux; int nb; int* off; int L;
    if (blockIdx.x == 0)      { aux = aux0; nb = nb0; off = off0; L = L0; }
    else if (blockIdx.x == 1) { aux = aux1; nb = nb1; off = off1; L = L1; }
    else                      { aux = aux2; nb = nb2; off = off2; L = L2; }
    int run = 0;
    for (int j = 0; j < nb; ++j) { int tv = aux[j]; aux[j] = run; run += tv; }
    off[L] = run;
}

__global__ __launch_bounds__(256) void scan_c(
    int* __restrict__ out0, const int* __restrict__ aux0, int L0, int nb0,
    int* __restrict__ out1, const int* __restrict__ aux1, int L1, int nb1,
    int* __restrict__ out2, const int* __restrict__ aux2, int L2)
{
    int b = blockIdx.x;
    int* out; const int* aux; int L;
    if (b < nb0)            { out = out0; aux = aux0; L = L0; }
    else if (b < nb0 + nb1) { b -= nb0; out = out1; aux = aux1; L = L1; }
    else                    { b -= nb0 + nb1; out = out2; aux = aux2; L = L2; }
    int add = aux[b];
    int base = b * SCAN_CHUNK + threadIdx.x * 16;
#pragma unroll
    for (int j = 0; j < 16; ++j)
        if (base + j < L) out[base + j] += add;
}

// ---- phase 3: meta-only CSR scatter (16 B/edge, the only big random write) ----
__global__ __launch_bounds__(256) void scatA_kernel(
    const int* __restrict__ ei, const float* __restrict__ attr,
    const int* __restrict__ cluster1, const int* __restrict__ cluster2,
    const int* __restrict__ doffs, const int* __restrict__ rank,
    const int* __restrict__ coff, const int* __restrict__ rankC,
    const int* __restrict__ c2off, const int* __restrict__ rank2,
    int* __restrict__ nidx, int* __restrict__ n1idx,
    int4* __restrict__ meta, int E, int N, int N1)
{
    int i = blockIdx.x * 256 + threadIdx.x;
    if (i < E) {
        int s = ei[i], d = ei[E + i];
        int p = doffs[d] + rank[i];

        float vx = attr[3 * i] * 2.f, vy = attr[3 * i + 1] * 2.f, vz = attr[3 * i + 2] * 2.f;
        float ix = fmaxf(fminf(floorf(vx), 1.f), 0.f);
        float iy = fmaxf(fminf(floorf(vy), 1.f), 0.f);
        float iz = fmaxf(fminf(floorf(vz), 1.f), 0.f);
        float fx = vx - ix, fy = vy - iy, fz = vz - iz;
        int ixi = (int)ix, iyi = (int)iy, izi = (int)iz;
        int ibase = ixi + 3 * iyi + 9 * izi;
        int slot  = ixi + 2 * iyi + 4 * izi;

        unsigned hfx = __half_as_ushort(__float2half_rn(fx));
        unsigned hfy = __half_as_ushort(__float2half_rn(fy));
        unsigned hfz = __half_as_ushort(__float2half_rn(fz));
        int s2 = cluster1[s];
        meta[p] = make_int4(s2 | (slot << 16), s | (ibase << 17),
                            (int)(hfx | (hfy << 16)), (int)hfz);
    }
    if (i < N)  nidx[coff[cluster1[i]] + rankC[i]] = i;
    if (i < N1) n1idx[c2off[cluster2[i]] + rank2[i]] = i;
}

// ---- level 1 fused: per (cluster, ch) recompute messages from meta, mean
//      per dst, +root/bias, ELU, max over members. No msg1/M1 arrays. ----
__global__ __launch_bounds__(256) void node1L_kernel(
    const int* __restrict__ coff, const int* __restrict__ nidx,
    const int* __restrict__ doffs, const int4* __restrict__ meta,
    const float2* __restrict__ x, const float* __restrict__ W1,
    const float* __restrict__ root1, const float* __restrict__ b1,
    const int* __restrict__ batch,
    float* __restrict__ x1c, int* __restrict__ batch1, int N1)
{
    __shared__ float lw[27 * W1_STRIDE];
    for (int i = threadIdx.x; i < 27 * 16; i += 256)
        lw[(i >> 4) * W1_STRIDE + (i & 15)] = W1[i];
    __syncthreads();

    int t = blockIdx.x * 256 + threadIdx.x;
    if (t >= N1 * 8) return;
    int c = t >> 3, ch = t & 7;
    int cb = coff[c], ce = coff[c + 1];
    float r0 = root1[ch], r1 = root1[8 + ch], bo = b1[ch];
    float hm = -INFINITY;
    int bm = 0;
    for (int idx = cb; idx < ce; ++idx) {
        int d = nidx[idx];
        int beg = doffs[d], end = doffs[d + 1];
        float acc = 0.f;
        for (int p = beg; p < end; ++p) {
            int4 m = meta[p];
            int src = m.y & 0x1FFFF, ibase = m.y >> 17;
            float fx = hlo(m.z), fy = hhi(m.z), fz = hlo(m.w);
            float2 xv = x[src];
            float wx0 = 1.f - fx, wy0 = 1.f - fy, wz0 = 1.f - fz;
            float ca = 0.f, cbv = 0.f;
#pragma unroll
            for (int j = 0; j < 8; ++j) {
                int cx = j & 1, cy = (j >> 1) & 1, cz = j >> 2;
                float w = (cx ? fx : wx0) * (cy ? fy : wy0) * (cz ? fz : wz0);
                int k = ibase + cx + 3 * cy + 9 * cz;
                ca  += w * lw[k * W1_STRIDE + ch];
                cbv += w * lw[k * W1_STRIDE + 8 + ch];
            }
            acc += ca * xv.x + cbv * xv.y;
        }
        float M1 = acc / fmaxf((float)(end - beg), 1.f);
        float2 xd = x[d];
        float h = eluf(M1 + xd.x * r0 + xd.y * r1 + bo);
        hm = fmaxf(hm, h);
        bm = max(bm, batch[d]);
    }
    if (ce == cb) hm = 0.f;  // empty cluster -> 0 (ref isfinite mask)
    x1c[t] = hm;
    if (ch == 0) batch1[c] = bm;
}

// ---- corner-expanded half table: tab[s2][slot(8)][ch(16)][corner(8)] half.
// One 256-B contiguous block per (s2,slot) serves a whole edge (all 16 ch,
// all 8 corners). Built once, streaming (82 MB). ----
__global__ __launch_bounds__(256) void xw2tab_kernel(
    const float4* __restrict__ x1c4, const float* __restrict__ W2,
    unsigned* __restrict__ tab, int N1)
{
    __shared__ float lw[27 * W2_STRIDE];             // 14.3 KB
    __shared__ float prod[16 * 27 * 17];             // 29.4 KB: [sl][row][ch(+pad)]
    for (int i = threadIdx.x; i < 27 * 128; i += 256)
        lw[(i >> 7) * W2_STRIDE + (i & 127)] = W2[i];
    __syncthreads();

    int sl = threadIdx.x >> 4, o = threadIdx.x & 15;
    int s2 = blockIdx.x * 16 + sl;
    if (s2 < N1) {
        float4 xa = x1c4[2 * s2], xb = x1c4[2 * s2 + 1];
        float xr[8] = {xa.x, xa.y, xa.z, xa.w, xb.x, xb.y, xb.z, xb.w};
        for (int row = 0; row < 27; ++row) {
            float sum = 0.f;
#pragma unroll
            for (int c8 = 0; c8 < 8; ++c8)
                sum += xr[c8] * lw[row * W2_STRIDE + c8 * 16 + o];
            prod[(sl * 27 + row) * 17 + o] = sum;
        }
    }
    __syncthreads();

    // emit 16 s2 x 512 dwords, coalesced
#pragma unroll
    for (int m = 0; m < 32; ++m) {
        int flat = m * 256 + threadIdx.x;            // [0, 8192)
        int sl2 = flat >> 9, rem = flat & 511;
        int slot = rem >> 6, oo = (rem >> 2) & 15, q = rem & 3;
        int s2o = blockIdx.x * 16 + sl2;
        if (s2o < N1) {
            int ibase = (slot & 1) + 3 * ((slot >> 1) & 1) + 9 * (slot >> 2);
            int cy = q & 1, cz = q >> 1;
            int r0 = ibase + 3 * cy + 9 * cz;        // x-corner 0; r0+1 = x-corner 1
            float v0 = prod[(sl2 * 27 + r0) * 17 + oo];
            float v1 = prod[(sl2 * 27 + r0 + 1) * 17 + oo];
            __half2 h2 = __floats2half2_rn(v0, v1);
            tab[(size_t)s2o * 512 + slot * 64 + oo * 4 + q] = *(unsigned*)&h2;
        }
    }
}

// ---- level 2 reduce: thread per (cluster, ch); ONE dwordx4 (16 B) per edge,
//      16-lane group reads one contiguous 256-B block ----
__global__ __launch_bounds__(256) void reduce2_kernel(
    const int* __restrict__ coff, const int* __restrict__ nidx,
    const int* __restrict__ doffs, const int4* __restrict__ meta,
    const unsigned* __restrict__ tab, float* __restrict__ M2, int N1)
{
    int t = blockIdx.x * 256 + threadIdx.x;
    if (t >= N1 * 16) return;
    int c = t >> 4, o = t & 15;
    float acc = 0.f;
    int cnt = 0;
    int cb = coff[c], ce = coff[c + 1];
    for (int idx = cb; idx < ce; ++idx) {
        int d = nidx[idx];
        int beg = doffs[d], end = doffs[d + 1];
        cnt += end - beg;
        for (int p = beg; p < end; ++p) {
            int4 m = meta[p];
            int s2 = m.x & 0xFFFF, slot = (m.x >> 16) & 7;
            float fx = hlo(m.z), fy = hhi(m.z), fz = hlo(m.w);
            const uint4 v = *(const uint4*)&tab[((size_t)s2 * 8 + slot) * 64 + o * 4];
            float wx0 = 1.f - fx, wy0 = 1.f - fy, wz0 = 1.f - fz;
            float f0x = hlo(v.x), f0y = hhi(v.x);
            float f1x = hlo(v.y), f1y = hhi(v.y);
            float f2x = hlo(v.z), f2y = hhi(v.z);
            float f3x = hlo(v.w), f3y = hhi(v.w);
            acc += (wy0 * wz0) * (wx0 * f0x + fx * f0y)
                 + (fy  * wz0) * (wx0 * f1x + fx * f1y)
                 + (wy0 * fz ) * (wx0 * f2x + fx * f2y)
                 + (fy  * fz ) * (wx0 * f3x + fx * f3y);
        }
    }
    M2[t] = acc / fmaxf((float)cnt, 1.f);
}

// ---- fallback (ws too small for table): blend from LDS W2 columns ----
__global__ __launch_bounds__(256) void reduce2_fb_kernel(
    const int* __restrict__ coff, const int* __restrict__ nidx,
    const int* __restrict__ doffs, const int4* __restrict__ meta,
    const float4* __restrict__ x1c4, const float* __restrict__ W2,
    float* __restrict__ M2, int N1)
{
    __shared__ float lw[27 * W2_STRIDE];
    for (int i = threadIdx.x; i < 27 * 128; i += 256)
        lw[(i >> 7) * W2_STRIDE + (i & 127)] = W2[i];
    __syncthreads();

    int t = blockIdx.x * 256 + threadIdx.x;
    if (t >= N1 * 16) return;
    int c = t >> 4, o = t & 15;
    float acc = 0.f;
    int cnt = 0;
    int cb = coff[c], ce = coff[c + 1];
    for (int idx = cb; idx < ce; ++idx) {
        int d = nidx[idx];
        int beg = doffs[d], end = doffs[d + 1];
        cnt += end - beg;
        for (int p = beg; p < end; ++p) {
            int4 m = meta[p];
            int s2 = m.x & 0xFFFF, ibase = m.y >> 17;
            float fx = hlo(m.z), fy = hhi(m.z), fz = hlo(m.w);
            float4 xa = x1c4[2 * s2], xb = x1c4[2 * s2 + 1];
            float xr[8] = {xa.x, xa.y, xa.z, xa.w, xb.x, xb.y, xb.z, xb.w};
            float wx0 = 1.f - fx, wy0 = 1.f - fy, wz0 = 1.f - fz;
#pragma unroll
            for (int j = 0; j < 8; ++j) {
                int cx = j & 1, cy = (j >> 1) & 1, cz = j >> 2;
                float w = (cx ? fx : wx0) * (cy ? fy : wy0) * (cz ? fz : wz0);
                const float* Wk = &lw[(ibase + cx + 3 * cy + 9 * cz) * W2_STRIDE + o];
                float s = 0.f;
#pragma unroll
                for (int c8 = 0; c8 < 8; ++c8) s += xr[c8] * Wk[c8 * 16];
                acc += w * s;
            }
        }
    }
    M2[t] = acc / fmaxf((float)cnt, 1.f);
}

// ---- level 2 node + pool + graph sum (LDS-binned; tiny global atomic tail) ----
__global__ __launch_bounds__(256) void node2_kernel(
    const int* __restrict__ c2off, const int* __restrict__ n1idx,
    const float* __restrict__ M2, const float* __restrict__ x1c,
    const float* __restrict__ root2, const float* __restrict__ b2,
    const int* __restrict__ batch1,
    float* __restrict__ gsum, float* __restrict__ gcnt, int N2)
{
    __shared__ float ls[16 * 16];
    __shared__ float lc[16];
    for (int i = threadIdx.x; i < 256; i += 256) ls[i] = 0.f;
    if (threadIdx.x < 16) lc[threadIdx.x] = 0.f;
    __syncthreads();

    int c2 = blockIdx.x * 256 + threadIdx.x;
    if (c2 < N2) {
        int cb = c2off[c2], ce = c2off[c2 + 1];
        float hm[16];
#pragma unroll
        for (int o = 0; o < 16; ++o) hm[o] = -INFINITY;
        int bm = 0;
        for (int idx = cb; idx < ce; ++idx) {
            int n1 = n1idx[idx];
            const float4* xr4 = (const float4*)&x1c[(size_t)n1 * 8];
            float4 xa = xr4[0], xb = xr4[1];
            float xr[8] = {xa.x, xa.y, xa.z, xa.w, xb.x, xb.y, xb.z, xb.w};
#pragma unroll
            for (int o = 0; o < 16; ++o) {
                float v = M2[(size_t)n1 * 16 + o] + b2[o];
#pragma unroll
                for (int c8 = 0; c8 < 8; ++c8) v += xr[c8] * root2[c8 * 16 + o];
                hm[o] = fmaxf(hm[o], eluf(v));
            }
            bm = max(bm, batch1[n1]);
        }
        if (ce == cb) {
#pragma unroll
            for (int o = 0; o < 16; ++o) hm[o] = 0.f;
        }
#pragma unroll
        for (int o = 0; o < 16; ++o) atomicAdd(&ls[bm * 16 + o], hm[o]);
        atomicAdd(&lc[bm], 1.f);
    }
    __syncthreads();
    for (int i = threadIdx.x; i < 256; i += 256) unsafeAtomicAdd(&gsum[i], ls[i]);
    if (threadIdx.x < 16) unsafeAtomicAdd(&gcnt[threadIdx.x], lc[threadIdx.x]);
}

// ---- head ----
__global__ __launch_bounds__(256) void head_kernel(
    const float* __restrict__ gsum, const float* __restrict__ gcnt,
    const float* __restrict__ fc1_w, const float* __restrict__ fc1_b,
    const float* __restrict__ fc2_w, const float* __restrict__ fc2_b,
    float* __restrict__ out, int B)
{
    __shared__ float g[16 * 16];
    __shared__ float h1[16 * 64];
    int t = threadIdx.x;
    if (t < B * 16) {
        int b = t >> 4;
        g[t] = gsum[t] / fmaxf(gcnt[b], 1.f);
    }
    __syncthreads();
    for (int j = t; j < B * 64; j += 256) {
        int b = j >> 6, jj = j & 63;
        float s = fc1_b[jj];
#pragma unroll
        for (int c = 0; c < 16; ++c) s += g[b * 16 + c] * fc1_w[c * 64 + jj];
        h1[j] = eluf(s);
    }
    __syncthreads();
    if (t < B) {
        float s = fc2_b[0];
#pragma unroll
        for (int j = 0; j < 64; ++j) s += h1[t * 64 + j] * fc2_w[j];
        out[t] = eluf(s);
    }
}

extern "C" void kernel_launch(void* const* d_in, const int* in_sizes, int n_in,
                              void* d_out, int out_size, void* d_ws, size_t ws_size,
                              hipStream_t stream)
{
    const float* x        = (const float*)d_in[0];
    const int*   ei       = (const int*)  d_in[1];
    const float* attr     = (const float*)d_in[2];
    const int*   batch    = (const int*)  d_in[3];
    const int*   cluster1 = (const int*)  d_in[4];
    const int*   cluster2 = (const int*)  d_in[5];
    const float* W1       = (const float*)d_in[6];
    const float* root1    = (const float*)d_in[7];
    const float* b1       = (const float*)d_in[8];
    const float* W2       = (const float*)d_in[9];
    const float* root2    = (const float*)d_in[10];
    const float* b2       = (const float*)d_in[11];
    const float* fc1_w    = (const float*)d_in[12];
    const float* fc1_b    = (const float*)d_in[13];
    const float* fc2_w    = (const float*)d_in[14];
    const float* fc2_b    = (const float*)d_in[15];

    const int N  = in_sizes[0] / 2;
    const int E  = in_sizes[1] / 2;
    const int N1 = in_sizes[5];
    const int N2 = N1 / 2;
    const int B  = out_size;

    const int nb0 = (N  + SCAN_CHUNK - 1) / SCAN_CHUNK;
    const int nb1 = (N1 + SCAN_CHUNK - 1) / SCAN_CHUNK;
    const int nb2 = (N2 + SCAN_CHUNK - 1) / SCAN_CHUNK;

    int* wi = (int*)d_ws;
    size_t off = 0;
    auto alloc = [&](size_t n, size_t align = 1) {
        off = (off + align - 1) & ~(align - 1);
        size_t r = off; off += n; return r;
    };
    // zero-init region
    int*   deg    = wi + alloc(N);
    int*   cdeg   = wi + alloc(N1);
    int*   c2deg  = wi + alloc(N2);
    float* gsum   = (float*)(wi + alloc((size_t)B * 16));
    float* gcnt   = (float*)(wi + alloc(B));
    const size_t zcount = off;
    // rest (fully overwritten before read)
    int*   doffs  = wi + alloc(N + 1);
    int*   coff   = wi + alloc(N1 + 1);
    int*   c2off  = wi + alloc(N2 + 1);
    int*   auxA   = wi + alloc(nb0);
    int*   auxB   = wi + alloc(nb1);
    int*   auxC   = wi + alloc(nb2);
    int*   rank   = wi + alloc(E);
    int*   rankC  = wi + alloc(N);
    int*   rank2  = wi + alloc(N1);
    int*   nidx   = wi + alloc(N);
    int*   n1idx  = wi + alloc(N1);
    int4*  meta   = (int4*)(wi + alloc((size_t)E * 4, 4));
    float* x1c    = (float*)(wi + alloc((size_t)N1 * 8, 4));
    int*   batch1 = wi + alloc(N1);
    float* M2     = (float*)(wi + alloc((size_t)N1 * 16, 4));
    unsigned* tab = (unsigned*)(wi + alloc((size_t)N1 * 512, 16));  // 82 MB half table
    const bool use_tab = (off * sizeof(int) <= ws_size);

    hipMemsetAsync(d_ws, 0, zcount * sizeof(int), stream);

    const int eb = (E + 255) / 256;
    hist_kernel<<<eb, 256, 0, stream>>>(ei, cluster1, cluster2,
                                        deg, rank, cdeg, rankC, c2deg, rank2, E, N, N1);
    scan_a<<<nb0 + nb1 + nb2, 256, 0, stream>>>(deg, doffs, auxA, N, nb0,
                                                cdeg, coff, auxB, N1, nb1,
                                                c2deg, c2off, auxC, N2);
    scan_b<<<3, 64, 0, stream>>>(auxA, nb0, doffs, N,
                                 auxB, nb1, coff, N1,
                                 auxC, nb2, c2off, N2);
    scan_c<<<nb0 + nb1 + nb2, 256, 0, stream>>>(doffs, auxA, N, nb0,
                                                coff, auxB, N1, nb1,
                                                c2off, auxC, N2);
    scatA_kernel<<<eb, 256, 0, stream>>>(ei, attr, cluster1, cluster2,
                                         doffs, rank, coff, rankC, c2off, rank2,
                                         nidx, n1idx, meta, E, N, N1);
    node1L_kernel<<<(N1 * 8 + 255) / 256, 256, 0, stream>>>(
        coff, nidx, doffs, meta, (const float2*)x, W1, root1, b1, batch,
        x1c, batch1, N1);
    if (use_tab) {
        xw2tab_kernel<<<(N1 + 15) / 16, 256, 0, stream>>>(
            (const float4*)x1c, W2, tab, N1);
        reduce2_kernel<<<(N1 * 16 + 255) / 256, 256, 0, stream>>>(
            coff, nidx, doffs, meta, tab, M2, N1);
    } else {
        reduce2_fb_kernel<<<(N1 * 16 + 255) / 256, 256, 0, stream>>>(
            coff, nidx, doffs, meta, (const float4*)x1c, W2, M2, N1);
    }
    node2_kernel<<<(N2 + 255) / 256, 256, 0, stream>>>(
        c2off, n1idx, M2, x1c, root2, b2, batch1, gsum, gcnt, N2);
    head_kernel<<<1, 256, 0, stream>>>(gsum, gcnt, fc1_w, fc1_b, fc2_w, fc2_b,
                                       (float*)d_out, B);
}